// Round 1
// baseline (469.926 us; speedup 1.0000x reference)
//
#include <hip/hip_runtime.h>
#include <hip/hip_bf16.h>

// Problem constants
#define B_N 16384
#define N_C 64
#define F_D 128
#define K_D 64

// ---------------------------------------------------------------------------
// Kernel 1: Modified Gram-Schmidt orthonormalization of each D_n (128x64).
// One block per cluster. D layout: D[n][i][j], i in [0,128) rows, j in [0,64) cols.
// Output Qg[n][i][j] (same layout as D): orthonormal columns spanning col(D_n).
// ---------------------------------------------------------------------------
__global__ __launch_bounds__(256) void mgs_kernel(const float* __restrict__ D,
                                                  float* __restrict__ Qg) {
    // column-major in LDS: col[j][i], stride 129 to break bank conflicts
    __shared__ float col[64 * 129];
    const int n = blockIdx.x;
    const int t = threadIdx.x;

    // load D[n] -> col[j*129 + i]  (global coalesced; LDS banks (j%32) distinct)
    for (int e = t; e < 8192; e += 256) {
        const int i = e >> 6, j = e & 63;
        col[j * 129 + i] = D[(size_t)n * 8192 + e];
    }
    __syncthreads();

    const int wave = t >> 6, lane = t & 63;
    for (int k = 0; k < 64; ++k) {
        const float* ck = &col[k * 129];
        const float a0 = ck[lane], a1 = ck[lane + 64];
        // redundant per-wave reduction of ||c_k||^2
        float nrm = a0 * a0 + a1 * a1;
        for (int off = 32; off; off >>= 1) nrm += __shfl_xor(nrm, off, 64);
        const float rinv = 1.0f / nrm;

        // project out c_k from later columns; waves take disjoint j
        for (int j = k + 1 + wave; j < 64; j += 4) {
            float* cj = &col[j * 129];
            const float b0 = cj[lane], b1 = cj[lane + 64];
            float d = a0 * b0 + a1 * b1;
            for (int off = 32; off; off >>= 1) d += __shfl_xor(d, off, 64);
            d *= rinv;
            cj[lane]      = b0 - d * a0;
            cj[lane + 64] = b1 - d * a1;
        }
        __syncthreads();
        if (t < 128) col[k * 129 + t] *= rsqrtf(nrm);   // normalize c_k
        __syncthreads();
    }

    // write Qg[n][i][j] = col[j][i]  (global coalesced; LDS banks (i+j)%32 distinct)
    for (int e = t; e < 8192; e += 256) {
        const int i = e >> 6, j = e & 63;
        Qg[(size_t)n * 8192 + e] = col[j * 129 + i];
    }
}

// ---------------------------------------------------------------------------
// Kernel 2: scores. S[n][b] = || Q_n^T x_b ||^2.
// Grid: (B/128 btiles, N/8 ngroups). Block 256 threads.
// Per n: GEMM tile Y[128 samples x 64 k] over F=128 (2 chunks of 64),
// 8x4 register micro-tile per thread, then squared-sum reduce over k.
// ---------------------------------------------------------------------------
#define XT_STRIDE 132   // 64 x 132 floats, 16B-aligned rows, conflict-free
#define QS_STRIDE 68    // 64 x 68 floats

__global__ __launch_bounds__(256) void scores_kernel(const float* __restrict__ x,
                                                     const float* __restrict__ Qg,
                                                     float* __restrict__ S) {
    __shared__ float xT[64 * XT_STRIDE];   // [i_local][r], 33792 B
    __shared__ float qs[64 * QS_STRIDE];   // [i_local][k], 17408 B

    const int t  = threadIdx.x;
    const int tk = t & 15;        // 16 k-groups of 4
    const int tr = t >> 4;        // 16 r-groups of 8
    const int b0 = blockIdx.x * 128;
    const int n0 = blockIdx.y * 8;

    for (int nn = 0; nn < 8; ++nn) {
        const int n = n0 + nn;
        float acc[8][4];
        #pragma unroll
        for (int rr = 0; rr < 8; ++rr)
            #pragma unroll
            for (int kk = 0; kk < 4; ++kk) acc[rr][kk] = 0.0f;

        for (int ch = 0; ch < 2; ++ch) {
            const int i0 = ch * 64;
            __syncthreads();   // previous phase's LDS reads complete

            // stage xT: x[b0+r][i0 + i] -> xT[i][r]
            {
                const int r = t >> 1, half = t & 1;
                const float4* src =
                    (const float4*)(x + (size_t)(b0 + r) * 128 + i0 + half * 32);
                #pragma unroll
                for (int c4 = 0; c4 < 8; ++c4) {
                    const float4 v = src[c4];
                    const int i = half * 32 + c4 * 4;
                    xT[(i + 0) * XT_STRIDE + r] = v.x;
                    xT[(i + 1) * XT_STRIDE + r] = v.y;
                    xT[(i + 2) * XT_STRIDE + r] = v.z;
                    xT[(i + 3) * XT_STRIDE + r] = v.w;
                }
            }
            // stage qs: Qg[n][i0+i][j] -> qs[i][j]  (coalesced, conflict-free)
            for (int e = t; e < 4096; e += 256) {
                const int i = e >> 6, j = e & 63;
                qs[i * QS_STRIDE + j] = Qg[(size_t)n * 8192 + i0 * 64 + e];
            }
            __syncthreads();

            #pragma unroll 8
            for (int i = 0; i < 64; ++i) {
                const float4 x0 = *(const float4*)&xT[i * XT_STRIDE + tr * 8];
                const float4 x1 = *(const float4*)&xT[i * XT_STRIDE + tr * 8 + 4];
                const float4 q0 = *(const float4*)&qs[i * QS_STRIDE + tk * 4];
                const float xv[8] = {x0.x, x0.y, x0.z, x0.w, x1.x, x1.y, x1.z, x1.w};
                const float qv[4] = {q0.x, q0.y, q0.z, q0.w};
                #pragma unroll
                for (int rr = 0; rr < 8; ++rr)
                    #pragma unroll
                    for (int kk = 0; kk < 4; ++kk)
                        acc[rr][kk] = fmaf(xv[rr], qv[kk], acc[rr][kk]);
            }
        }

        // partial squared sums over this thread's 4 k's
        float ps[8];
        #pragma unroll
        for (int rr = 0; rr < 8; ++rr) {
            float v = 0.0f;
            #pragma unroll
            for (int kk = 0; kk < 4; ++kk) v += acc[rr][kk] * acc[rr][kk];
            ps[rr] = v;
        }

        __syncthreads();            // all compute reads of xT done
        float* sq = xT;             // alias: [16 kgroups][129] partial sums
        #pragma unroll
        for (int rr = 0; rr < 8; ++rr) sq[tk * 129 + tr * 8 + rr] = ps[rr];
        __syncthreads();

        if (t < 128) {
            float v = 0.0f;
            #pragma unroll
            for (int g = 0; g < 16; ++g) v += sq[g * 129 + t];
            S[(size_t)n * B_N + b0 + t] = v;
        }
    }
}

// ---------------------------------------------------------------------------
// Kernel 3: per-sample argmax over clusters + loss partials.
// Block 256 threads handles 256 samples. err_b = ||x_b||^2 - max_n S[n][b].
// Reference uses argmin with first-index tie-break => strict > when scanning
// ascending n keeps the earliest maximizer.
// ---------------------------------------------------------------------------
__global__ __launch_bounds__(256) void reduce_kernel(const float* __restrict__ x,
                                                     const float* __restrict__ S,
                                                     float* __restrict__ out,
                                                     float* __restrict__ partials) {
    __shared__ float nr[256];
    __shared__ float wsum[4];
    const int t = threadIdx.x;
    const int b0 = blockIdx.x * 256;

    // coalesced row norms
    for (int rr = 0; rr < 2; ++rr) {
        const int r = rr * 128 + (t >> 1);
        const int half = t & 1;
        const float4* p = (const float4*)(x + (size_t)(b0 + r) * 128 + half * 64);
        float s = 0.0f;
        #pragma unroll
        for (int c = 0; c < 16; ++c) {
            const float4 v = p[c];
            s += v.x * v.x + v.y * v.y + v.z * v.z + v.w * v.w;
        }
        s += __shfl_xor(s, 1, 64);
        if (half == 0) nr[r] = s;
    }
    __syncthreads();

    const int b = b0 + t;
    float best = -1e30f;
    int lab = 0;
    for (int n = 0; n < 64; ++n) {
        const float v = S[(size_t)n * B_N + b];
        if (v > best) { best = v; lab = n; }
    }
    out[1 + b] = (float)lab;

    float err = nr[t] - best;
    for (int off = 32; off; off >>= 1) err += __shfl_xor(err, off, 64);
    if ((t & 63) == 0) wsum[t >> 6] = err;
    __syncthreads();
    if (t == 0) partials[blockIdx.x] = wsum[0] + wsum[1] + wsum[2] + wsum[3];
}

__global__ void final_kernel(const float* __restrict__ partials,
                             float* __restrict__ out) {
    const int t = threadIdx.x;   // 64 threads
    float v = partials[t];
    for (int off = 32; off; off >>= 1) v += __shfl_xor(v, off, 64);
    if (t == 0) out[0] = v;
}

// ---------------------------------------------------------------------------
extern "C" void kernel_launch(void* const* d_in, const int* in_sizes, int n_in,
                              void* d_out, int out_size, void* d_ws, size_t ws_size,
                              hipStream_t stream) {
    const float* x = (const float*)d_in[0];   // [16384, 128]
    const float* D = (const float*)d_in[1];   // [64, 128, 64]
    float* out = (float*)d_out;               // [1 + 16384]

    float* ws = (float*)d_ws;
    float* Qg = ws;                            // 524288 floats
    float* S  = ws + 524288;                   // 1048576 floats
    float* partials = ws + 524288 + 1048576;   // 64 floats

    mgs_kernel<<<64, 256, 0, stream>>>(D, Qg);
    scores_kernel<<<dim3(128, 8), 256, 0, stream>>>(x, Qg, S);
    reduce_kernel<<<64, 256, 0, stream>>>(x, S, out, partials);
    final_kernel<<<1, 64, 0, stream>>>(partials, out);
}

// Round 2
// 419.389 us; speedup vs baseline: 1.1205x; 1.1205x over previous
//
#include <hip/hip_runtime.h>
#include <hip/hip_bf16.h>

// Problem constants
#define B_N 16384
#define N_C 64
#define F_D 128
#define K_D 64

#define LPAD 65   // G/L leading-dim pad (odd => conflict-free column access)

// ---------------------------------------------------------------------------
// Kernel 1: per-cluster orthonormal factor Q_n = D_n * L_n^{-T}, where
// G_n = D_n^T D_n = L_n L_n^T (Cholesky). span(Q_n) = span(D_n), Q orthonormal,
// so S[n][b] = ||Q_n^T x_b||^2 gives the projection norm (same as MGS round 1).
// One block per cluster (64 blocks x 256 threads).
// Phases: load D -> gram -> Cholesky -> back-substitution (W = L^{-T}) -> GEMM.
// ---------------------------------------------------------------------------
__global__ __launch_bounds__(256) void prep_kernel(const float* __restrict__ D,
                                                   float* __restrict__ Qg) {
    __shared__ __align__(16) float ds[128 * 64];  // D_n staging; first 4096 floats
                                                  // later aliased as B = W (64x64)
    __shared__ __align__(16) float G[64 * LPAD];  // gram -> L (lower); col 64 = 1/L[i][i]

    const int n = blockIdx.x;
    const int t = threadIdx.x;
    const float* Dn = D + (size_t)n * 8192;

    // ---- load D_n (row-major 128x64) ----
    for (int e4 = t; e4 < 2048; e4 += 256)
        *(float4*)&ds[e4 * 4] = ((const float4*)Dn)[e4];
    __syncthreads();

    // ---- gram: G[a][b] = sum_i ds[i][a]*ds[i][b] (full symmetric) ----
    {
        const int a0 = (t & 15) * 4, b0 = (t >> 4) * 4;
        float acc[4][4] = {};
        for (int i = 0; i < 128; ++i) {
            const float4 av = *(const float4*)&ds[i * 64 + a0];
            const float4 bv = *(const float4*)&ds[i * 64 + b0];
            const float aa[4] = {av.x, av.y, av.z, av.w};
            const float bb[4] = {bv.x, bv.y, bv.z, bv.w};
            #pragma unroll
            for (int p = 0; p < 4; ++p)
                #pragma unroll
                for (int q = 0; q < 4; ++q) acc[p][q] = fmaf(aa[p], bb[q], acc[p][q]);
        }
        __syncthreads();   // all gram reads of ds done before B-zero below
        #pragma unroll
        for (int p = 0; p < 4; ++p)
            #pragma unroll
            for (int q = 0; q < 4; ++q) G[(a0 + p) * LPAD + b0 + q] = acc[p][q];
        // zero the B region (aliases first 16 KB of ds)
        for (int e = t; e < 4096; e += 256) ds[e] = 0.0f;
    }
    __syncthreads();

    // ---- Cholesky: lower(G) <- L, G[k][64] <- 1/L[k][k] ----
    {
        const int wv = t >> 6, lane = t & 63;
        for (int k = 0; k < 64; ++k) {
            if (t == 0) G[k * LPAD + 64] = 1.0f / sqrtf(G[k * LPAD + k]);
            __syncthreads();
            const float inv = G[k * LPAD + 64];
            const int i = k + t;
            if (i < 64) G[i * LPAD + k] *= inv;   // column k -> L[i][k] (diag -> sqrt)
            __syncthreads();
            // full-square trailing update: G[i][j] -= L[i][k]*L[j][k], i,j > k
            for (int i2 = k + 1 + wv; i2 < 64; i2 += 4) {
                const float ci = G[i2 * LPAD + k];           // broadcast
                const int j = k + 1 + lane;
                if (j < 64) G[i2 * LPAD + j] -= ci * G[j * LPAD + k];
            }
            __syncthreads();
        }
    }

    // ---- back-substitution: B[:,j] solves L^T w = e_j  =>  B = W = L^{-T} ----
    // B[k][j] = 0 for k > j (pre-zeroed). Uniform lockstep: lane j = column j.
    float* Bm = ds;   // 64x64, stride 64
    if (t < 64) {
        const int j = t;
        for (int i = 63; i >= 0; --i) {
            float s = 0.0f;
            for (int k = i + 1; k < 64; ++k)                   // zeros beyond j are free
                s = fmaf(G[k * LPAD + i], Bm[k * 64 + j], s);  // L[k][i] broadcast
            const float e = (i == j) ? 1.0f : 0.0f;
            Bm[i * 64 + j] = (e - s) * G[i * LPAD + 64];       // * 1/L[i][i]
        }
    }
    __syncthreads();

    // ---- Q_n = D_n * B (128x64 x 64x64); A re-read from L2-hot global ----
    {
        const int row = t >> 1, jh = (t & 1) * 32;
        float acc[32];
        #pragma unroll
        for (int c = 0; c < 32; ++c) acc[c] = 0.0f;
        const float* An = Dn + (size_t)row * 64;
        for (int k4 = 0; k4 < 16; ++k4) {
            const float4 av = *(const float4*)(An + k4 * 4);
            const float a4[4] = {av.x, av.y, av.z, av.w};
            #pragma unroll
            for (int kk = 0; kk < 4; ++kk) {
                const int k = k4 * 4 + kk;
                const float4* Br = (const float4*)&Bm[k * 64 + jh];
                #pragma unroll
                for (int c = 0; c < 8; ++c) {
                    const float4 bv = Br[c];
                    acc[c * 4 + 0] = fmaf(a4[kk], bv.x, acc[c * 4 + 0]);
                    acc[c * 4 + 1] = fmaf(a4[kk], bv.y, acc[c * 4 + 1]);
                    acc[c * 4 + 2] = fmaf(a4[kk], bv.z, acc[c * 4 + 2]);
                    acc[c * 4 + 3] = fmaf(a4[kk], bv.w, acc[c * 4 + 3]);
                }
            }
        }
        float* Qn = Qg + (size_t)n * 8192 + (size_t)row * 64 + jh;
        #pragma unroll
        for (int c = 0; c < 8; ++c)
            *(float4*)(Qn + c * 4) =
                make_float4(acc[c * 4], acc[c * 4 + 1], acc[c * 4 + 2], acc[c * 4 + 3]);
    }
}

// ---------------------------------------------------------------------------
// Kernel 2: scores. S[n][b] = || Q_n^T x_b ||^2.   (unchanged from round 1)
// ---------------------------------------------------------------------------
#define XT_STRIDE 132   // 64 x 132 floats, 16B-aligned rows, conflict-free
#define QS_STRIDE 68    // 64 x 68 floats

__global__ __launch_bounds__(256) void scores_kernel(const float* __restrict__ x,
                                                     const float* __restrict__ Qg,
                                                     float* __restrict__ S) {
    __shared__ float xT[64 * XT_STRIDE];   // [i_local][r], 33792 B
    __shared__ float qs[64 * QS_STRIDE];   // [i_local][k], 17408 B

    const int t  = threadIdx.x;
    const int tk = t & 15;        // 16 k-groups of 4
    const int tr = t >> 4;        // 16 r-groups of 8
    const int b0 = blockIdx.x * 128;
    const int n0 = blockIdx.y * 8;

    for (int nn = 0; nn < 8; ++nn) {
        const int n = n0 + nn;
        float acc[8][4];
        #pragma unroll
        for (int rr = 0; rr < 8; ++rr)
            #pragma unroll
            for (int kk = 0; kk < 4; ++kk) acc[rr][kk] = 0.0f;

        for (int ch = 0; ch < 2; ++ch) {
            const int i0 = ch * 64;
            __syncthreads();   // previous phase's LDS reads complete

            // stage xT: x[b0+r][i0 + i] -> xT[i][r]
            {
                const int r = t >> 1, half = t & 1;
                const float4* src =
                    (const float4*)(x + (size_t)(b0 + r) * 128 + i0 + half * 32);
                #pragma unroll
                for (int c4 = 0; c4 < 8; ++c4) {
                    const float4 v = src[c4];
                    const int i = half * 32 + c4 * 4;
                    xT[(i + 0) * XT_STRIDE + r] = v.x;
                    xT[(i + 1) * XT_STRIDE + r] = v.y;
                    xT[(i + 2) * XT_STRIDE + r] = v.z;
                    xT[(i + 3) * XT_STRIDE + r] = v.w;
                }
            }
            // stage qs: Qg[n][i0+i][j] -> qs[i][j]  (coalesced, conflict-free)
            for (int e = t; e < 4096; e += 256) {
                const int i = e >> 6, j = e & 63;
                qs[i * QS_STRIDE + j] = Qg[(size_t)n * 8192 + i0 * 64 + e];
            }
            __syncthreads();

            #pragma unroll 8
            for (int i = 0; i < 64; ++i) {
                const float4 x0 = *(const float4*)&xT[i * XT_STRIDE + tr * 8];
                const float4 x1 = *(const float4*)&xT[i * XT_STRIDE + tr * 8 + 4];
                const float4 q0 = *(const float4*)&qs[i * QS_STRIDE + tk * 4];
                const float xv[8] = {x0.x, x0.y, x0.z, x0.w, x1.x, x1.y, x1.z, x1.w};
                const float qv[4] = {q0.x, q0.y, q0.z, q0.w};
                #pragma unroll
                for (int rr = 0; rr < 8; ++rr)
                    #pragma unroll
                    for (int kk = 0; kk < 4; ++kk)
                        acc[rr][kk] = fmaf(xv[rr], qv[kk], acc[rr][kk]);
            }
        }

        // partial squared sums over this thread's 4 k's
        float ps[8];
        #pragma unroll
        for (int rr = 0; rr < 8; ++rr) {
            float v = 0.0f;
            #pragma unroll
            for (int kk = 0; kk < 4; ++kk) v += acc[rr][kk] * acc[rr][kk];
            ps[rr] = v;
        }

        __syncthreads();            // all compute reads of xT done
        float* sq = xT;             // alias: [16 kgroups][129] partial sums
        #pragma unroll
        for (int rr = 0; rr < 8; ++rr) sq[tk * 129 + tr * 8 + rr] = ps[rr];
        __syncthreads();

        if (t < 128) {
            float v = 0.0f;
            #pragma unroll
            for (int g = 0; g < 16; ++g) v += sq[g * 129 + t];
            S[(size_t)n * B_N + b0 + t] = v;
        }
    }
}

// ---------------------------------------------------------------------------
// Kernel 3: per-sample argmax over clusters + loss partials.  (unchanged)
// ---------------------------------------------------------------------------
__global__ __launch_bounds__(256) void reduce_kernel(const float* __restrict__ x,
                                                     const float* __restrict__ S,
                                                     float* __restrict__ out,
                                                     float* __restrict__ partials) {
    __shared__ float nr[256];
    __shared__ float wsum[4];
    const int t = threadIdx.x;
    const int b0 = blockIdx.x * 256;

    // coalesced row norms
    for (int rr = 0; rr < 2; ++rr) {
        const int r = rr * 128 + (t >> 1);
        const int half = t & 1;
        const float4* p = (const float4*)(x + (size_t)(b0 + r) * 128 + half * 64);
        float s = 0.0f;
        #pragma unroll
        for (int c = 0; c < 16; ++c) {
            const float4 v = p[c];
            s += v.x * v.x + v.y * v.y + v.z * v.z + v.w * v.w;
        }
        s += __shfl_xor(s, 1, 64);
        if (half == 0) nr[r] = s;
    }
    __syncthreads();

    const int b = b0 + t;
    float best = -1e30f;
    int lab = 0;
    for (int n = 0; n < 64; ++n) {
        const float v = S[(size_t)n * B_N + b];
        if (v > best) { best = v; lab = n; }
    }
    out[1 + b] = (float)lab;

    float err = nr[t] - best;
    for (int off = 32; off; off >>= 1) err += __shfl_xor(err, off, 64);
    if ((t & 63) == 0) wsum[t >> 6] = err;
    __syncthreads();
    if (t == 0) partials[blockIdx.x] = wsum[0] + wsum[1] + wsum[2] + wsum[3];
}

__global__ void final_kernel(const float* __restrict__ partials,
                             float* __restrict__ out) {
    const int t = threadIdx.x;   // 64 threads
    float v = partials[t];
    for (int off = 32; off; off >>= 1) v += __shfl_xor(v, off, 64);
    if (t == 0) out[0] = v;
}

// ---------------------------------------------------------------------------
extern "C" void kernel_launch(void* const* d_in, const int* in_sizes, int n_in,
                              void* d_out, int out_size, void* d_ws, size_t ws_size,
                              hipStream_t stream) {
    const float* x = (const float*)d_in[0];   // [16384, 128]
    const float* D = (const float*)d_in[1];   // [64, 128, 64]
    float* out = (float*)d_out;               // [1 + 16384]

    float* ws = (float*)d_ws;
    float* Qg = ws;                            // 524288 floats
    float* S  = ws + 524288;                   // 1048576 floats
    float* partials = ws + 524288 + 1048576;   // 64 floats

    prep_kernel<<<64, 256, 0, stream>>>(D, Qg);
    scores_kernel<<<dim3(128, 8), 256, 0, stream>>>(x, Qg, S);
    reduce_kernel<<<64, 256, 0, stream>>>(x, S, out, partials);
    final_kernel<<<1, 64, 0, stream>>>(partials, out);
}

// Round 3
// 257.544 us; speedup vs baseline: 1.8246x; 1.6284x over previous
//
#include <hip/hip_runtime.h>
#include <hip/hip_bf16.h>

#define B_N 16384
#define N_C 64
#define F_D 128
#define K_D 64
#define TAU 0.25f

typedef __attribute__((ext_vector_type(4))) float f32x4;
typedef __attribute__((ext_vector_type(8))) short s16x8;

__device__ __forceinline__ void gl_lds16(const void* g, void* l) {
    __builtin_amdgcn_global_load_lds(
        (const __attribute__((address_space(1))) void*)g,
        (__attribute__((address_space(3))) void*)l, 16, 0, 0);
}

__device__ __forceinline__ unsigned short bf16_bits(float v) {
    __hip_bfloat16 h = __float2bfloat16(v);
    return *reinterpret_cast<unsigned short*>(&h);
}
__device__ __forceinline__ float bf16_val(float v) {
    __hip_bfloat16 h = __float2bfloat16(v);
    return __bfloat162float(h);
}

// ---------------------------------------------------------------------------
// Kernel 1: x -> xh, xl (bf16 split) + row norms; zero the flag counter.
// gid handles 64 contiguous floats (half a row).
// ---------------------------------------------------------------------------
__global__ __launch_bounds__(256) void convert_kernel(const float* __restrict__ x,
                                                      unsigned short* __restrict__ xh,
                                                      unsigned short* __restrict__ xl,
                                                      float* __restrict__ nrm,
                                                      int* __restrict__ cnt) {
    const int gid = blockIdx.x * 256 + threadIdx.x;   // 0..32767
    if (gid == 0) *cnt = 0;
    const size_t base = (size_t)gid * 64;
    float s = 0.0f;
    #pragma unroll
    for (int c = 0; c < 16; ++c) {
        const f32x4 v = ((const f32x4*)(x + base))[c];
        s += v.x * v.x + v.y * v.y + v.z * v.z + v.w * v.w;
        ushort4 h, l;
        h.x = bf16_bits(v.x); l.x = bf16_bits(v.x - bf16_val(v.x));
        h.y = bf16_bits(v.y); l.y = bf16_bits(v.y - bf16_val(v.y));
        h.z = bf16_bits(v.z); l.z = bf16_bits(v.z - bf16_val(v.z));
        h.w = bf16_bits(v.w); l.w = bf16_bits(v.w - bf16_val(v.w));
        ((ushort4*)(xh + base))[c] = h;
        ((ushort4*)(xl + base))[c] = l;
    }
    s += __shfl_xor(s, 1, 64);
    if ((gid & 1) == 0) nrm[gid >> 1] = s;
}

// ---------------------------------------------------------------------------
// Kernel 2: per-cluster prep. Q_n = D_n * L^{-T} (orthonormal basis).
// Register Cholesky (wave 0, row-distributed, no barriers), register L^{-1}
// (lane-per-column), then Q GEMM (all waves) + bf16 transpose for B-operand.
// ---------------------------------------------------------------------------
__global__ __launch_bounds__(256, 1) void prep_kernel(const float* __restrict__ D,
                                                      float* __restrict__ Qg,
                                                      unsigned short* __restrict__ Bht,
                                                      unsigned short* __restrict__ Blt) {
    __shared__ __align__(16) float ds[8192];          // D staging -> W (64x68) -> free
    __shared__ __align__(16) float G[64 * 68 + 64];   // gram -> L; tail 64 = 1/L[i][i]
    const int n = blockIdx.x, t = threadIdx.x;
    const int w = t >> 6, lane = t & 63;
    const float* Dn = D + (size_t)n * 8192;

    for (int e = t; e < 2048; e += 256) ((f32x4*)ds)[e] = ((const f32x4*)Dn)[e];
    __syncthreads();

    // gram: G[a][b] = sum_i D[i][a] D[i][b], stride 68
    {
        const int a0 = (t & 15) * 4, b0 = (t >> 4) * 4;
        float acc[4][4] = {};
        for (int i = 0; i < 128; ++i) {
            const f32x4 av = *(const f32x4*)&ds[i * 64 + a0];
            const f32x4 bv = *(const f32x4*)&ds[i * 64 + b0];
            const float aa[4] = {av.x, av.y, av.z, av.w};
            const float bb[4] = {bv.x, bv.y, bv.z, bv.w};
            #pragma unroll
            for (int p = 0; p < 4; ++p)
                #pragma unroll
                for (int q = 0; q < 4; ++q) acc[p][q] = fmaf(aa[p], bb[q], acc[p][q]);
        }
        #pragma unroll
        for (int p = 0; p < 4; ++p)
            #pragma unroll
            for (int q = 0; q < 4; ++q) G[(a0 + p) * 68 + b0 + q] = acc[p][q];
    }
    __syncthreads();

    // ---- wave 0: Cholesky + L^{-1}, register resident, no block barriers ----
    if (w == 0) {
        float g[64];            // lane i holds row i of G (then L)
        #pragma unroll
        for (int j = 0; j < 64; ++j) g[j] = G[lane * 68 + j];
        float dinv = 0.0f;
        #pragma unroll
        for (int k = 0; k < 64; ++k) {
            const float dk = __shfl(g[k], k, 64);
            const float rinv = 1.0f / sqrtf(dk);
            const float cik = g[k] * rinv;      // L[i][k] (valid for i >= k)
            g[k] = cik;
            if (lane == k) dinv = rinv;         // 1/L[k][k]
            #pragma unroll
            for (int j = k + 1; j < 64; ++j) {
                const float cjk = __shfl(cik, j, 64);
                g[j] -= cik * cjk;
            }
        }
        #pragma unroll
        for (int j = 0; j < 64; ++j) G[lane * 68 + j] = g[j];   // L rows
        G[64 * 68 + lane] = dinv;

        // M = L^{-1}, lane = column c; m[] in regs, L broadcast from LDS
        const int c = lane;
        float m[64];
        #pragma unroll
        for (int i = 0; i < 64; ++i) {
            float s = (i == c) ? 1.0f : 0.0f;
            #pragma unroll
            for (int k = 0; k < i; ++k) s = fmaf(-G[i * 68 + k], m[k], s);
            m[i] = s * G[64 * 68 + i];
        }
        // W[k][j] = M[j][k]: lane c provides W row c = m[j] over j
        #pragma unroll
        for (int j = 0; j < 64; ++j) ds[c * 68 + j] = m[j];
    }
    __syncthreads();

    // ---- Q = D (global, L2-hot) * W (ds, stride 68) ----
    const int row = t >> 1, jh = (t & 1) * 32;
    float acc[32];
    #pragma unroll
    for (int c = 0; c < 32; ++c) acc[c] = 0.0f;
    {
        const float* An = Dn + (size_t)row * 64;
        for (int k4 = 0; k4 < 16; ++k4) {
            const f32x4 av = *(const f32x4*)(An + k4 * 4);
            const float a4[4] = {av.x, av.y, av.z, av.w};
            #pragma unroll
            for (int kk = 0; kk < 4; ++kk) {
                const int k = k4 * 4 + kk;
                const f32x4* Br = (const f32x4*)&ds[k * 68 + jh];
                #pragma unroll
                for (int c = 0; c < 8; ++c) {
                    const f32x4 bv = Br[c];
                    acc[c * 4 + 0] = fmaf(a4[kk], bv.x, acc[c * 4 + 0]);
                    acc[c * 4 + 1] = fmaf(a4[kk], bv.y, acc[c * 4 + 1]);
                    acc[c * 4 + 2] = fmaf(a4[kk], bv.z, acc[c * 4 + 2]);
                    acc[c * 4 + 3] = fmaf(a4[kk], bv.w, acc[c * 4 + 3]);
                }
            }
        }
        float* Qn = Qg + (size_t)n * 8192 + (size_t)row * 64 + jh;
        #pragma unroll
        for (int c = 0; c < 8; ++c)
            *(f32x4*)(Qn + c * 4) = *(f32x4*)&acc[c * 4];
    }

    // ---- transposed bf16 (Bht/Blt rows = [n*64+j][i]) via LDS, two i-halves ----
    float* T = G;   // reuse: 64 x 65 floats fits in G region
    for (int half = 0; half < 2; ++half) {
        __syncthreads();
        if ((row >> 6) == half) {
            const int r = row & 63;
            #pragma unroll
            for (int c = 0; c < 32; ++c) T[(jh + c) * 65 + r] = acc[c];
        }
        __syncthreads();
        for (int e = t; e < 4096; e += 256) {
            const int j = e >> 6, i = e & 63;
            const float v = T[j * 65 + i];
            const size_t o = ((size_t)n * 64 + j) * 128 + half * 64 + i;
            Bht[o] = bf16_bits(v);
            Blt[o] = bf16_bits(v - bf16_val(v));
        }
    }
}

// ---------------------------------------------------------------------------
// Kernel 3: MFMA scores. S[n][b] = ||Q_n^T x_b||^2 via split-bf16:
// xh*Qh + xh*Ql + xl*Qh, K=384 as 6 BK=64 chunks. 128x128 tile, 4 waves.
// LDS XOR-swizzled [row][kblock^(row&7)] so global_load_lds(16B) stages
// contiguously AND ds_read_b128 is 2-way-max on banks.
// ---------------------------------------------------------------------------
__global__ __launch_bounds__(256) void gemm_scores(const unsigned short* __restrict__ xh,
                                                   const unsigned short* __restrict__ xl,
                                                   const unsigned short* __restrict__ Bht,
                                                   const unsigned short* __restrict__ Blt,
                                                   float* __restrict__ S) {
    __shared__ unsigned short ldsA[128 * 64];   // 16 KB
    __shared__ unsigned short ldsB[128 * 64];   // 16 KB
    const int t = threadIdx.x, w = t >> 6, lane = t & 63;
    const int m0 = blockIdx.x * 128;
    const int n0 = blockIdx.y * 128;
    const int wm = w & 1, wn = w >> 1;

    f32x4 acc[4][4];
    #pragma unroll
    for (int mt = 0; mt < 4; ++mt)
        #pragma unroll
        for (int nt = 0; nt < 4; ++nt) acc[mt][nt] = (f32x4){0.f, 0.f, 0.f, 0.f};

    const unsigned short* Asrc[6] = {xh, xh, xh, xh, xl, xl};
    const unsigned short* Bsrc[6] = {Bht, Bht, Blt, Blt, Bht, Bht};
    const int koff[6] = {0, 64, 0, 64, 0, 64};

    #pragma unroll 1
    for (int it = 0; it < 6; ++it) {
        const unsigned short* A = Asrc[it];
        const unsigned short* Bp = Bsrc[it];
        const int ko = koff[it];
        __syncthreads();   // previous iter's ds_reads done
        #pragma unroll
        for (int q = 0; q < 4; ++q) {
            const int r = w * 32 + q * 8 + (lane >> 3);
            const int cb = (lane & 7) ^ (r & 7);
            gl_lds16(A + (size_t)(m0 + r) * 128 + ko + cb * 8,
                     &ldsA[(w * 32 + q * 8) * 64]);
            gl_lds16(Bp + (size_t)(n0 + r) * 128 + ko + cb * 8,
                     &ldsB[(w * 32 + q * 8) * 64]);
        }
        __syncthreads();   // staging complete (vmcnt drained by barrier)
        #pragma unroll
        for (int ks = 0; ks < 2; ++ks) {
            s16x8 af[4], bf[4];
            #pragma unroll
            for (int mt = 0; mt < 4; ++mt) {
                const int r = wm * 64 + mt * 16 + (lane & 15);
                const int s = (ks * 4 + (lane >> 4)) ^ (r & 7);
                af[mt] = *(const s16x8*)&ldsA[r * 64 + s * 8];
            }
            #pragma unroll
            for (int nt = 0; nt < 4; ++nt) {
                const int r = wn * 64 + nt * 16 + (lane & 15);
                const int s = (ks * 4 + (lane >> 4)) ^ (r & 7);
                bf[nt] = *(const s16x8*)&ldsB[r * 64 + s * 8];
            }
            #pragma unroll
            for (int mt = 0; mt < 4; ++mt)
                #pragma unroll
                for (int nt = 0; nt < 4; ++nt)
                    acc[mt][nt] = __builtin_amdgcn_mfma_f32_16x16x32_bf16(
                        af[mt], bf[nt], acc[mt][nt], 0, 0, 0);
        }
    }

    // epilogue: per wave, its 64 columns = one cluster; squared-sum over n
    const int nc = blockIdx.y * 2 + wn;
    #pragma unroll
    for (int mt = 0; mt < 4; ++mt) {
        #pragma unroll
        for (int rg = 0; rg < 4; ++rg) {
            float p = 0.0f;
            #pragma unroll
            for (int nt = 0; nt < 4; ++nt) {
                const float v = acc[mt][nt][rg];
                p += v * v;
            }
            p += __shfl_xor(p, 1, 64);
            p += __shfl_xor(p, 2, 64);
            p += __shfl_xor(p, 4, 64);
            p += __shfl_xor(p, 8, 64);
            if ((lane & 15) == 0) {
                const int m = wm * 64 + mt * 16 + (lane >> 4) * 4 + rg;
                S[(size_t)nc * B_N + m0 + m] = p;
            }
        }
    }
}

// ---------------------------------------------------------------------------
// Kernel 4: per-sample argmax + margin flagging + loss partials.
// ---------------------------------------------------------------------------
__global__ __launch_bounds__(256) void argmax_kernel(const float* __restrict__ Sa,
                                                     const float* __restrict__ nrm,
                                                     float* __restrict__ out,
                                                     float* __restrict__ partials,
                                                     int* __restrict__ cnt,
                                                     int* __restrict__ flags) {
    __shared__ float wsum[4];
    const int t = threadIdx.x;
    const int b = blockIdx.x * 256 + t;
    float v1 = -1e30f, v2 = -1e30f;
    int n1 = 0;
    for (int n = 0; n < 64; ++n) {
        const float v = Sa[(size_t)n * B_N + b];
        if (v > v1) { v2 = v1; v1 = v; n1 = n; }
        else v2 = fmaxf(v2, v);
    }
    out[1 + b] = (float)n1;
    if (v1 - v2 < TAU) { const int idx = atomicAdd(cnt, 1); flags[idx] = b; }
    float err = nrm[b] - v1;
    for (int off = 32; off; off >>= 1) err += __shfl_xor(err, off, 64);
    if ((t & 63) == 0) wsum[t >> 6] = err;
    __syncthreads();
    if (t == 0) partials[blockIdx.x] = wsum[0] + wsum[1] + wsum[2] + wsum[3];
}

__global__ void final_kernel(const float* __restrict__ partials,
                             float* __restrict__ out) {
    const int t = threadIdx.x;
    float v = partials[t];
    for (int off = 32; off; off >>= 1) v += __shfl_xor(v, off, 64);
    if (t == 0) out[0] = v;
}

// ---------------------------------------------------------------------------
// Kernel 5: exact fp32 rescore of flagged samples (wave per sample).
// Recomputes labels among clusters within TAU of max, ascending-n tie-break.
// ---------------------------------------------------------------------------
__global__ __launch_bounds__(256) void rescore_kernel(const float* __restrict__ Sa,
                                                      const float* __restrict__ x,
                                                      const float* __restrict__ Qg,
                                                      float* __restrict__ out,
                                                      const int* __restrict__ cnt,
                                                      const int* __restrict__ flags) {
    const int t = threadIdx.x, w = t >> 6, lane = t & 63;
    const int wid = blockIdx.x * 4 + w;
    const int nflag = *cnt;
    for (int f = wid; f < nflag; f += 256) {
        const int b = flags[f];
        const float v = Sa[(size_t)lane * B_N + b];
        float v1 = v;
        for (int off = 32; off; off >>= 1) v1 = fmaxf(v1, __shfl_xor(v1, off, 64));
        const bool fl = (v1 - v) < TAU;
        unsigned long long mask = __ballot(fl);
        float best = -1e30f;
        int bn = 0;
        while (mask) {
            const int nn = (int)__builtin_ctzll(mask);
            mask &= mask - 1;
            const float* Qn = Qg + (size_t)nn * 8192;
            const float* xb = x + (size_t)b * 128;
            float dot = 0.0f;
            #pragma unroll 8
            for (int i = 0; i < 128; ++i)
                dot = fmaf(Qn[i * 64 + lane], xb[i], dot);
            float sv = dot * dot;
            for (int off = 32; off; off >>= 1) sv += __shfl_xor(sv, off, 64);
            if (sv > best) { best = sv; bn = nn; }
        }
        if (lane == 0) out[1 + b] = (float)bn;
    }
}

// ---------------------------------------------------------------------------
extern "C" void kernel_launch(void* const* d_in, const int* in_sizes, int n_in,
                              void* d_out, int out_size, void* d_ws, size_t ws_size,
                              hipStream_t stream) {
    const float* x = (const float*)d_in[0];   // [16384, 128]
    const float* D = (const float*)d_in[1];   // [64, 128, 64]
    float* out = (float*)d_out;               // [1 + 16384]

    char* ws = (char*)d_ws;
    unsigned short* xh  = (unsigned short*)(ws);                 // 4 MB
    unsigned short* xl  = (unsigned short*)(ws + (4u << 20));    // 4 MB
    unsigned short* Bht = (unsigned short*)(ws + (8u << 20));    // 1 MB
    unsigned short* Blt = (unsigned short*)(ws + (9u << 20));    // 1 MB
    float* Qg           = (float*)(ws + (10u << 20));            // 2 MB
    float* Sa           = (float*)(ws + (12u << 20));            // 4 MB
    float* nrm          = (float*)(ws + (16u << 20));            // 64 KB
    float* partials     = (float*)(ws + (16u << 20) + 65536);    // 256 B
    int* cnt            = (int*)(ws + (16u << 20) + 65536 + 256);
    int* flags          = (int*)(ws + (16u << 20) + 65536 + 512);

    convert_kernel<<<128, 256, 0, stream>>>(x, xh, xl, nrm, cnt);
    prep_kernel<<<64, 256, 0, stream>>>(D, Qg, Bht, Blt);
    gemm_scores<<<dim3(128, 32), 256, 0, stream>>>(xh, xl, Bht, Blt, Sa);
    argmax_kernel<<<64, 256, 0, stream>>>(Sa, nrm, out, partials, cnt, flags);
    final_kernel<<<1, 64, 0, stream>>>(partials, out);
    rescore_kernel<<<64, 256, 0, stream>>>(Sa, x, Qg, out, cnt, flags);
}

// Round 4
// 234.639 us; speedup vs baseline: 2.0028x; 1.0976x over previous
//
#include <hip/hip_runtime.h>
#include <hip/hip_bf16.h>

#define B_N 16384
#define TAU 0.25f
#define GS 68     // G leading dim (floats), 16B-aligned rows
#define YS 132    // Y leading dim (floats), 16B-aligned rows

typedef float f32x4 __attribute__((ext_vector_type(4)));
typedef short s16x8 __attribute__((ext_vector_type(8)));

__device__ __forceinline__ void gl_lds16(const void* g, void* l) {
    __builtin_amdgcn_global_load_lds(
        (const __attribute__((address_space(1))) void*)g,
        (__attribute__((address_space(3))) void*)l, 16, 0, 0);
}

__device__ __forceinline__ unsigned short bf16_bits(float v) {
    __hip_bfloat16 h = __float2bfloat16(v);
    return *reinterpret_cast<unsigned short*>(&h);
}

// ---------------------------------------------------------------------------
// Kernel 1 (merged): blocks 0..63 = per-cluster prep; blocks 64..191 = convert.
//
// Prep: G = Dn^T Dn; blocked Cholesky G = L L^T (8-col panels: wave-synchronous
// panel factor + all-thread rank-8 trailing update); TRSM L*Y = Dn^T column-
// parallel (Y = Q^T, 64x128, in-place in LDS); emit Bht (bf16, B-operand rows
// [n*64+j][i]) and Qg fp32 [n][i][j] for exact rescoring.
// Convert: x -> xh bf16 + row norms; zero cnt and out[0].
// Small code on purpose: R3's fully-unrolled prep (~10k instrs) was I-cache-
// thrash-bound at 1 wave/CU.
// ---------------------------------------------------------------------------
__global__ __launch_bounds__(256) void prep_convert(const float* __restrict__ x,
                                                    const float* __restrict__ D,
                                                    unsigned short* __restrict__ xh,
                                                    float* __restrict__ nrm,
                                                    float* __restrict__ Qg,
                                                    unsigned short* __restrict__ Bht,
                                                    int* __restrict__ cnt,
                                                    float* __restrict__ out) {
    __shared__ __align__(16) float G[64 * GS + 64];   // gram->L; tail 64 = 1/L[i][i]
    __shared__ __align__(16) float Y[64 * YS];        // D^T staging -> Q^T (in place)
    const int t = threadIdx.x;

    if (blockIdx.x >= 64) {
        // ---------------- convert path ----------------
        const int gid = (blockIdx.x - 64) * 256 + t;   // 0..32767 half-rows
        if (gid == 0) { *cnt = 0; out[0] = 0.0f; }
        const size_t base = (size_t)gid * 64;
        float s = 0.0f;
        #pragma unroll
        for (int c = 0; c < 16; ++c) {
            const f32x4 v = ((const f32x4*)(x + base))[c];
            s += v.x * v.x + v.y * v.y + v.z * v.z + v.w * v.w;
            ushort4 h;
            h.x = bf16_bits(v.x); h.y = bf16_bits(v.y);
            h.z = bf16_bits(v.z); h.w = bf16_bits(v.w);
            ((ushort4*)(xh + base))[c] = h;
        }
        s += __shfl_xor(s, 1, 64);
        if ((gid & 1) == 0) nrm[gid >> 1] = s;
        return;
    }

    // ---------------- prep path ----------------
    const int n = blockIdx.x;
    const float* Dn = D + (size_t)n * 8192;

    // Phase A: stage D^T into Y: Y[j][c] = Dn[c][j]
    for (int e = t; e < 8192; e += 256) {
        const int c = e >> 6, j = e & 63;
        Y[j * YS + c] = Dn[e];
    }

    // Phase B: gram from global (Dn is L1/L2-hot, 32 KB)
    {
        const int a0 = (t & 15) * 4, b0 = (t >> 4) * 4;
        float acc[4][4] = {};
        #pragma unroll 4
        for (int i = 0; i < 128; ++i) {
            const f32x4 av = *(const f32x4*)(Dn + i * 64 + a0);
            const f32x4 bv = *(const f32x4*)(Dn + i * 64 + b0);
            const float aa[4] = {av.x, av.y, av.z, av.w};
            const float bb[4] = {bv.x, bv.y, bv.z, bv.w};
            #pragma unroll
            for (int p = 0; p < 4; ++p)
                #pragma unroll
                for (int q = 0; q < 4; ++q) acc[p][q] = fmaf(aa[p], bb[q], acc[p][q]);
        }
        #pragma unroll
        for (int p = 0; p < 4; ++p)
            #pragma unroll
            for (int q = 0; q < 4; ++q) G[(a0 + p) * GS + b0 + q] = acc[p][q];
    }
    __syncthreads();

    // Phase C: blocked Cholesky, 8 panels of 8 columns
    for (int p = 0; p < 8; ++p) {
        const int pb = p * 8;
        if (t < 64) {   // wave 0, wave-synchronous panel factor
            for (int kk = 0; kk < 8; ++kk) {
                const int k = pb + kk;
                const float rinv = 1.0f / sqrtf(G[k * GS + k]);
                const float lik = G[t * GS + k] * rinv;
                if (t >= k) G[t * GS + k] = lik;
                if (t == k) G[64 * GS + k] = rinv;
                for (int j = k + 1; j < pb + 8; ++j) {
                    const float ljk = G[j * GS + k];      // broadcast
                    if (t > k) G[t * GS + j] -= lik * ljk;
                }
            }
        }
        __syncthreads();
        const int base = pb + 8;
        if (base < 64) {   // rank-8 trailing update, all 256 threads
            for (int i = base + (t >> 5); i < 64; i += 8) {
                const f32x4 Li0 = *(const f32x4*)&G[i * GS + pb];
                const f32x4 Li1 = *(const f32x4*)&G[i * GS + pb + 4];
                for (int j = base + (t & 31); j < 64; j += 32) {
                    const f32x4 Lj0 = *(const f32x4*)&G[j * GS + pb];
                    const f32x4 Lj1 = *(const f32x4*)&G[j * GS + pb + 4];
                    float s = G[i * GS + j];
                    s -= Li0.x * Lj0.x + Li0.y * Lj0.y + Li0.z * Lj0.z + Li0.w * Lj0.w;
                    s -= Li1.x * Lj1.x + Li1.y * Lj1.y + Li1.z * Lj1.z + Li1.w * Lj1.w;
                    G[i * GS + j] = s;
                }
            }
        }
        __syncthreads();
    }

    // Phase D: TRSM L*Y = D^T, column-parallel (thread = column c), in place.
    // Columns independent; waves 0-1 only; no barriers needed inside.
    if (t < 128) {
        const int c = t;
        for (int j = 0; j < 64; ++j) {
            float s = Y[j * YS + c];
            #pragma unroll 4
            for (int k = 0; k < j; ++k)
                s -= G[j * GS + k] * Y[k * YS + c];
            Y[j * YS + c] = s * G[64 * GS + j];
        }
    }
    __syncthreads();

    // Phase E: outputs. Y[j][i] = Q^T -> Bht rows [n*64+j][i] (bf16) and
    // Qg[n][i][j] fp32 for rescore.
    for (int e = t; e < 8192; e += 256) {
        const int j = e >> 7, i = e & 127;
        Bht[((size_t)n * 64 + j) * 128 + i] = bf16_bits(Y[j * YS + i]);
    }
    for (int e = t; e < 8192; e += 256) {
        const int i = e >> 6, j = e & 63;
        Qg[(size_t)n * 8192 + e] = Y[j * YS + i];
    }
}

// ---------------------------------------------------------------------------
// Kernel 2: MFMA scores, single bf16 term. S[n][b] = ||Qh_n^T xh_b||^2.
// K=128 (2 phases of BK=64), 128x128 tile, 4 waves, XOR-swizzled LDS.
// ---------------------------------------------------------------------------
__global__ __launch_bounds__(256) void gemm_scores(const unsigned short* __restrict__ xh,
                                                   const unsigned short* __restrict__ Bht,
                                                   float* __restrict__ S) {
    __shared__ unsigned short ldsA[128 * 64];   // 16 KB
    __shared__ unsigned short ldsB[128 * 64];   // 16 KB
    const int t = threadIdx.x, w = t >> 6, lane = t & 63;
    const int m0 = blockIdx.x * 128;
    const int n0 = blockIdx.y * 128;
    const int wm = w & 1, wn = w >> 1;

    f32x4 acc[4][4];
    #pragma unroll
    for (int mt = 0; mt < 4; ++mt)
        #pragma unroll
        for (int nt = 0; nt < 4; ++nt) acc[mt][nt] = (f32x4){0.f, 0.f, 0.f, 0.f};

    #pragma unroll 1
    for (int it = 0; it < 2; ++it) {
        const int ko = it * 64;
        __syncthreads();   // previous iter's ds_reads done
        #pragma unroll
        for (int q = 0; q < 4; ++q) {
            const int r = w * 32 + q * 8 + (lane >> 3);
            const int cb = (lane & 7) ^ (r & 7);
            gl_lds16(xh + (size_t)(m0 + r) * 128 + ko + cb * 8,
                     &ldsA[(w * 32 + q * 8) * 64]);
            gl_lds16(Bht + (size_t)(n0 + r) * 128 + ko + cb * 8,
                     &ldsB[(w * 32 + q * 8) * 64]);
        }
        __syncthreads();   // staging complete
        #pragma unroll
        for (int ks = 0; ks < 2; ++ks) {
            s16x8 af[4], bf[4];
            #pragma unroll
            for (int mt = 0; mt < 4; ++mt) {
                const int r = wm * 64 + mt * 16 + (lane & 15);
                const int s = (ks * 4 + (lane >> 4)) ^ (r & 7);
                af[mt] = *(const s16x8*)&ldsA[r * 64 + s * 8];
            }
            #pragma unroll
            for (int nt = 0; nt < 4; ++nt) {
                const int r = wn * 64 + nt * 16 + (lane & 15);
                const int s = (ks * 4 + (lane >> 4)) ^ (r & 7);
                bf[nt] = *(const s16x8*)&ldsB[r * 64 + s * 8];
            }
            #pragma unroll
            for (int mt = 0; mt < 4; ++mt)
                #pragma unroll
                for (int nt = 0; nt < 4; ++nt)
                    acc[mt][nt] = __builtin_amdgcn_mfma_f32_16x16x32_bf16(
                        af[mt], bf[nt], acc[mt][nt], 0, 0, 0);
        }
    }

    // epilogue: per wave, its 64 columns = one cluster; squared-sum over them
    const int nc = blockIdx.y * 2 + wn;
    #pragma unroll
    for (int mt = 0; mt < 4; ++mt) {
        #pragma unroll
        for (int rg = 0; rg < 4; ++rg) {
            float p = 0.0f;
            #pragma unroll
            for (int nt = 0; nt < 4; ++nt) {
                const float v = acc[mt][nt][rg];
                p += v * v;
            }
            p += __shfl_xor(p, 1, 64);
            p += __shfl_xor(p, 2, 64);
            p += __shfl_xor(p, 4, 64);
            p += __shfl_xor(p, 8, 64);
            if ((lane & 15) == 0) {
                const int m = wm * 64 + mt * 16 + (lane >> 4) * 4 + rg;
                S[(size_t)nc * B_N + m0 + m] = p;
            }
        }
    }
}

// ---------------------------------------------------------------------------
// Kernel 3: per-sample argmax + margin flagging + loss (atomic into out[0]).
// ---------------------------------------------------------------------------
__global__ __launch_bounds__(256) void argmax_kernel(const float* __restrict__ Sa,
                                                     const float* __restrict__ nrm,
                                                     float* __restrict__ out,
                                                     int* __restrict__ cnt,
                                                     int* __restrict__ flags) {
    __shared__ float wsum[4];
    const int t = threadIdx.x;
    const int b = blockIdx.x * 256 + t;
    float v1 = -1e30f, v2 = -1e30f;
    int n1 = 0;
    for (int n = 0; n < 64; ++n) {
        const float v = Sa[(size_t)n * B_N + b];
        if (v > v1) { v2 = v1; v1 = v; n1 = n; }
        else v2 = fmaxf(v2, v);
    }
    out[1 + b] = (float)n1;
    if (v1 - v2 < TAU) { const int idx = atomicAdd(cnt, 1); flags[idx] = b; }
    float err = nrm[b] - v1;
    for (int off = 32; off; off >>= 1) err += __shfl_xor(err, off, 64);
    if ((t & 63) == 0) wsum[t >> 6] = err;
    __syncthreads();
    if (t == 0) atomicAdd(out, wsum[0] + wsum[1] + wsum[2] + wsum[3]);
}

// ---------------------------------------------------------------------------
// Kernel 4: exact fp32 rescore of flagged samples (wave per sample):
// fixes labels AND corrects their loss terms to exact (adds v1_approx - S_exact).
// ---------------------------------------------------------------------------
__global__ __launch_bounds__(256) void rescore_kernel(const float* __restrict__ Sa,
                                                      const float* __restrict__ x,
                                                      const float* __restrict__ Qg,
                                                      float* __restrict__ out,
                                                      const int* __restrict__ cnt,
                                                      const int* __restrict__ flags) {
    const int t = threadIdx.x, w = t >> 6, lane = t & 63;
    const int wid = blockIdx.x * 4 + w;
    const int nflag = *cnt;
    for (int f = wid; f < nflag; f += 256) {
        const int b = flags[f];
        const float v = Sa[(size_t)lane * B_N + b];
        float v1 = v;
        for (int off = 32; off; off >>= 1) v1 = fmaxf(v1, __shfl_xor(v1, off, 64));
        const bool fl = (v1 - v) < TAU;
        unsigned long long mask = __ballot(fl);
        float best = -1e30f;
        int bn = 0;
        while (mask) {
            const int nn = (int)__builtin_ctzll(mask);
            mask &= mask - 1;
            const float* Qn = Qg + (size_t)nn * 8192;
            const float* xb = x + (size_t)b * 128;
            float dot = 0.0f;
            #pragma unroll 8
            for (int i = 0; i < 128; ++i)
                dot = fmaf(Qn[i * 64 + lane], xb[i], dot);
            float sv = dot * dot;
            for (int off = 32; off; off >>= 1) sv += __shfl_xor(sv, off, 64);
            if (sv > best) { best = sv; bn = nn; }
        }
        if (lane == 0) {
            out[1 + b] = (float)bn;
            atomicAdd(out, v1 - best);   // replace approx loss term with exact
        }
    }
}

// ---------------------------------------------------------------------------
extern "C" void kernel_launch(void* const* d_in, const int* in_sizes, int n_in,
                              void* d_out, int out_size, void* d_ws, size_t ws_size,
                              hipStream_t stream) {
    const float* x = (const float*)d_in[0];   // [16384, 128]
    const float* D = (const float*)d_in[1];   // [64, 128, 64]
    float* out = (float*)d_out;               // [1 + 16384]

    char* ws = (char*)d_ws;
    unsigned short* xh  = (unsigned short*)(ws);                 // 4 MB
    unsigned short* Bht = (unsigned short*)(ws + (4u << 20));    // 1 MB
    float* Qg           = (float*)(ws + (5u << 20));             // 2 MB
    float* Sa           = (float*)(ws + (7u << 20));             // 4 MB
    float* nrm          = (float*)(ws + (11u << 20));            // 64 KB
    int* cnt            = (int*)(ws + (11u << 20) + 65536);
    int* flags          = (int*)(ws + (11u << 20) + 65536 + 256);

    prep_convert<<<192, 256, 0, stream>>>(x, D, xh, nrm, Qg, Bht, cnt, out);
    gemm_scores<<<dim3(128, 32), 256, 0, stream>>>(xh, Bht, Sa);
    argmax_kernel<<<64, 256, 0, stream>>>(Sa, nrm, out, cnt, flags);
    rescore_kernel<<<64, 256, 0, stream>>>(Sa, x, Qg, out, cnt, flags);
}

// Round 5
// 215.179 us; speedup vs baseline: 2.1839x; 1.0904x over previous
//
#include <hip/hip_runtime.h>
#include <hip/hip_bf16.h>

#define B_N 16384
#define TAU 0.25f
#define GS 68     // G leading dim (floats); 16B-aligned rows
#define YS 132    // Y leading dim (floats); 16B-aligned rows

typedef float f32x4 __attribute__((ext_vector_type(4)));
typedef short s16x8 __attribute__((ext_vector_type(8)));

__device__ __forceinline__ void gl_lds16(const void* g, void* l) {
    __builtin_amdgcn_global_load_lds(
        (const __attribute__((address_space(1))) void*)g,
        (__attribute__((address_space(3))) void*)l, 16, 0, 0);
}

__device__ __forceinline__ unsigned short bf16_bits(float v) {
    __hip_bfloat16 h = __float2bfloat16(v);
    return *reinterpret_cast<unsigned short*>(&h);
}

// ---------------------------------------------------------------------------
// Kernel 1 (merged): blocks 0..63 = per-cluster prep; blocks 64..191 = convert.
//
// Prep computes Q_n^T = L_n^{-1} D_n^T (orthonormal rows spanning D_n's cols):
//   A: stage D^T into LDS (Y)            [coalesced global, once]
//   B: gram G = D^T D from LDS
//   C: Cholesky G = L L^T — 8x8 panel factors REGISTER-resident in wave 0
//      (shuffle chains, no LDS round-trips) + all-thread rank-8 trailing updates
//   D: invert the 8 diagonal 8x8 blocks independently (64 threads, registers)
//   E: Q^T = L^{-1} D^T by block forward substitution, one thread per column —
//      zero barriers, zero cross-thread deps (each column self-contained)
//   F: emit Bht (bf16 B-operand rows [n*64+j][i]) + Qg fp32 [n][i][j]
// R4's 71 us was chained-LDS-latency in the serial core; every chain step here
// is register/shuffle or same-thread.
// ---------------------------------------------------------------------------
__global__ __launch_bounds__(256) void prep_convert(const float* __restrict__ x,
                                                    const float* __restrict__ D,
                                                    unsigned short* __restrict__ xh,
                                                    float* __restrict__ nrm,
                                                    float* __restrict__ Qg,
                                                    unsigned short* __restrict__ Bht,
                                                    float* __restrict__ out) {
    __shared__ __align__(16) float Y[64 * YS];        // D^T -> Q^T (in place)
    __shared__ __align__(16) float G[64 * GS + 64];   // gram -> L; tail = 1/L[i][i]
    __shared__ __align__(16) float Lti[8 * 8 * 8];    // 8x8 diag-block inverses
    const int t = threadIdx.x;

    if (blockIdx.x >= 64) {
        // ---------------- convert path ----------------
        const int gid = (blockIdx.x - 64) * 256 + t;   // 0..32767 half-rows
        if (gid == 0) out[0] = 0.0f;
        const size_t base = (size_t)gid * 64;
        float s = 0.0f;
        #pragma unroll
        for (int c = 0; c < 16; ++c) {
            const f32x4 v = ((const f32x4*)(x + base))[c];
            s += v.x * v.x + v.y * v.y + v.z * v.z + v.w * v.w;
            ushort4 h;
            h.x = bf16_bits(v.x); h.y = bf16_bits(v.y);
            h.z = bf16_bits(v.z); h.w = bf16_bits(v.w);
            ((ushort4*)(xh + base))[c] = h;
        }
        s += __shfl_xor(s, 1, 64);
        if ((gid & 1) == 0) nrm[gid >> 1] = s;
        return;
    }

    // ---------------- prep path ----------------
    const int n = blockIdx.x;
    const float* Dn = D + (size_t)n * 8192;

    // Phase A: Y[j][c] = Dn[c][j]  (coalesced f32x4 global reads)
    for (int e4 = t; e4 < 2048; e4 += 256) {
        const int c = e4 >> 4, j4 = (e4 & 15) * 4;
        const f32x4 v = ((const f32x4*)Dn)[e4];
        Y[(j4 + 0) * YS + c] = v.x;
        Y[(j4 + 1) * YS + c] = v.y;
        Y[(j4 + 2) * YS + c] = v.z;
        Y[(j4 + 3) * YS + c] = v.w;
    }
    __syncthreads();

    // Phase B: gram G[a][b] = sum_c Y[a][c]*Y[b][c]
    {
        const int a0 = (t & 15) * 4, b0 = (t >> 4) * 4;
        float acc[4][4] = {};
        for (int c4 = 0; c4 < 32; ++c4) {
            f32x4 A[4], Bv[4];
            #pragma unroll
            for (int p = 0; p < 4; ++p) {
                A[p]  = *(const f32x4*)&Y[(a0 + p) * YS + c4 * 4];
                Bv[p] = *(const f32x4*)&Y[(b0 + p) * YS + c4 * 4];
            }
            #pragma unroll
            for (int p = 0; p < 4; ++p)
                #pragma unroll
                for (int q = 0; q < 4; ++q)
                    acc[p][q] += A[p].x * Bv[q].x + A[p].y * Bv[q].y +
                                 A[p].z * Bv[q].z + A[p].w * Bv[q].w;
        }
        #pragma unroll
        for (int p = 0; p < 4; ++p)
            #pragma unroll
            for (int q = 0; q < 4; ++q) G[(a0 + p) * GS + b0 + q] = acc[p][q];
    }
    __syncthreads();

    // Phase C: blocked Cholesky, register-resident 8x8 panel factors
    for (int p8 = 0; p8 < 8; ++p8) {
        const int pb = p8 * 8;
        if (t < 64) {   // wave 0
            const int lane = t;
            const f32x4 v0 = *(const f32x4*)&G[lane * GS + pb];
            const f32x4 v1 = *(const f32x4*)&G[lane * GS + pb + 4];
            float g[8] = {v0.x, v0.y, v0.z, v0.w, v1.x, v1.y, v1.z, v1.w};
            #pragma unroll
            for (int kk = 0; kk < 8; ++kk) {
                const int k = pb + kk;
                const float dk = __shfl(g[kk], k, 64);
                const float rinv = 1.0f / sqrtf(dk);
                const float lik = g[kk] * rinv;
                g[kk] = lik;
                if (lane == 0) G[64 * GS + k] = rinv;
                #pragma unroll
                for (int jj = kk + 1; jj < 8; ++jj) {
                    const float ljk = __shfl(lik, pb + jj, 64);
                    g[jj] -= lik * ljk;
                }
            }
            *(f32x4*)&G[lane * GS + pb]     = (f32x4){g[0], g[1], g[2], g[3]};
            *(f32x4*)&G[lane * GS + pb + 4] = (f32x4){g[4], g[5], g[6], g[7]};
        }
        __syncthreads();
        const int base = pb + 8;
        if (base < 64) {   // rank-8 trailing update, all 256 threads
            for (int i = base + (t >> 5); i < 64; i += 8) {
                const f32x4 Li0 = *(const f32x4*)&G[i * GS + pb];
                const f32x4 Li1 = *(const f32x4*)&G[i * GS + pb + 4];
                for (int j = base + (t & 31); j < 64; j += 32) {
                    const f32x4 Lj0 = *(const f32x4*)&G[j * GS + pb];
                    const f32x4 Lj1 = *(const f32x4*)&G[j * GS + pb + 4];
                    float s = G[i * GS + j];
                    s -= Li0.x * Lj0.x + Li0.y * Lj0.y + Li0.z * Lj0.z + Li0.w * Lj0.w;
                    s -= Li1.x * Lj1.x + Li1.y * Lj1.y + Li1.z * Lj1.z + Li1.w * Lj1.w;
                    G[i * GS + j] = s;
                }
            }
        }
        __syncthreads();
    }

    // Phase D: invert 8x8 diagonal blocks independently. t<64: block bi, col c.
    if (t < 64) {
        const int bi = t >> 3, c = t & 7;
        const int base = bi * 8;
        float m[8];
        #pragma unroll
        for (int r = 0; r < 8; ++r) {
            float s = (r == c) ? 1.0f : 0.0f;
            #pragma unroll
            for (int k = 0; k < r; ++k)
                s -= G[(base + r) * GS + base + k] * m[k];
            m[r] = s * G[64 * GS + base + r];
        }
        #pragma unroll
        for (int r = 0; r < 8; ++r) Lti[(base + r) * 8 + c] = m[r];
    }
    __syncthreads();

    // Phase E: Q^T = L^{-1} D^T, block forward substitution; thread = column c.
    // No barriers: each column depends only on its own prior writes.
    if (t < 128) {
        const int c = t;
        for (int i = 0; i < 8; ++i) {
            float Tv[8];
            #pragma unroll
            for (int r = 0; r < 8; ++r) Tv[r] = Y[(i * 8 + r) * YS + c];
            for (int k = 0; k < i; ++k) {
                #pragma unroll
                for (int kk = 0; kk < 8; ++kk) {
                    const float z = Y[(k * 8 + kk) * YS + c];
                    #pragma unroll
                    for (int r = 0; r < 8; ++r)
                        Tv[r] -= G[(i * 8 + r) * GS + k * 8 + kk] * z;
                }
            }
            #pragma unroll
            for (int r = 0; r < 8; ++r) {
                float z = 0.0f;
                #pragma unroll
                for (int rp = 0; rp <= r; ++rp)
                    z += Lti[(i * 8 + r) * 8 + rp] * Tv[rp];
                Y[(i * 8 + r) * YS + c] = z;
            }
        }
    }
    __syncthreads();

    // Phase F: outputs. Y[j][i] = Q^T.
    for (int e = t; e < 8192; e += 256) {
        const int j = e >> 7, i = e & 127;
        Bht[((size_t)n * 64 + j) * 128 + i] = bf16_bits(Y[j * YS + i]);
    }
    for (int e = t; e < 8192; e += 256) {
        const int i = e >> 6, j = e & 63;
        Qg[(size_t)n * 8192 + e] = Y[j * YS + i];
    }
}

// ---------------------------------------------------------------------------
// Kernel 2: MFMA scores. S[n][b] = ||Qh_n^T xh_b||^2. K=128 (2 x BK=64),
// 128x128 tile, 4 waves, XOR-swizzled LDS. (unchanged, known-good)
// ---------------------------------------------------------------------------
__global__ __launch_bounds__(256) void gemm_scores(const unsigned short* __restrict__ xh,
                                                   const unsigned short* __restrict__ Bht,
                                                   float* __restrict__ S) {
    __shared__ unsigned short ldsA[128 * 64];   // 16 KB
    __shared__ unsigned short ldsB[128 * 64];   // 16 KB
    const int t = threadIdx.x, w = t >> 6, lane = t & 63;
    const int m0 = blockIdx.x * 128;
    const int n0 = blockIdx.y * 128;
    const int wm = w & 1, wn = w >> 1;

    f32x4 acc[4][4];
    #pragma unroll
    for (int mt = 0; mt < 4; ++mt)
        #pragma unroll
        for (int nt = 0; nt < 4; ++nt) acc[mt][nt] = (f32x4){0.f, 0.f, 0.f, 0.f};

    #pragma unroll 1
    for (int it = 0; it < 2; ++it) {
        const int ko = it * 64;
        __syncthreads();
        #pragma unroll
        for (int q = 0; q < 4; ++q) {
            const int r = w * 32 + q * 8 + (lane >> 3);
            const int cb = (lane & 7) ^ (r & 7);
            gl_lds16(xh + (size_t)(m0 + r) * 128 + ko + cb * 8,
                     &ldsA[(w * 32 + q * 8) * 64]);
            gl_lds16(Bht + (size_t)(n0 + r) * 128 + ko + cb * 8,
                     &ldsB[(w * 32 + q * 8) * 64]);
        }
        __syncthreads();
        #pragma unroll
        for (int ks = 0; ks < 2; ++ks) {
            s16x8 af[4], bf[4];
            #pragma unroll
            for (int mt = 0; mt < 4; ++mt) {
                const int r = wm * 64 + mt * 16 + (lane & 15);
                const int s = (ks * 4 + (lane >> 4)) ^ (r & 7);
                af[mt] = *(const s16x8*)&ldsA[r * 64 + s * 8];
            }
            #pragma unroll
            for (int nt = 0; nt < 4; ++nt) {
                const int r = wn * 64 + nt * 16 + (lane & 15);
                const int s = (ks * 4 + (lane >> 4)) ^ (r & 7);
                bf[nt] = *(const s16x8*)&ldsB[r * 64 + s * 8];
            }
            #pragma unroll
            for (int mt = 0; mt < 4; ++mt)
                #pragma unroll
                for (int nt = 0; nt < 4; ++nt)
                    acc[mt][nt] = __builtin_amdgcn_mfma_f32_16x16x32_bf16(
                        af[mt], bf[nt], acc[mt][nt], 0, 0, 0);
        }
    }

    const int nc = blockIdx.y * 2 + wn;
    #pragma unroll
    for (int mt = 0; mt < 4; ++mt) {
        #pragma unroll
        for (int rg = 0; rg < 4; ++rg) {
            float p = 0.0f;
            #pragma unroll
            for (int nt = 0; nt < 4; ++nt) {
                const float v = acc[mt][nt][rg];
                p += v * v;
            }
            p += __shfl_xor(p, 1, 64);
            p += __shfl_xor(p, 2, 64);
            p += __shfl_xor(p, 4, 64);
            p += __shfl_xor(p, 8, 64);
            if ((lane & 15) == 0) {
                const int m = wm * 64 + mt * 16 + (lane >> 4) * 4 + rg;
                S[(size_t)nc * B_N + m0 + m] = p;
            }
        }
    }
}

// ---------------------------------------------------------------------------
// Kernel 3: per-sample argmax + loss, with in-block exact rescoring of
// near-tie samples (block-local flag list in LDS; one atomicAdd per block).
// ---------------------------------------------------------------------------
__global__ __launch_bounds__(256) void argmax_rescore(const float* __restrict__ Sa,
                                                      const float* __restrict__ nrm,
                                                      const float* __restrict__ x,
                                                      const float* __restrict__ Qg,
                                                      float* __restrict__ out) {
    __shared__ int sflags[256];
    __shared__ int scnt;
    __shared__ float ssum[4];
    __shared__ float scorr[4];
    const int t = threadIdx.x, w = t >> 6, lane = t & 63;
    const int b = blockIdx.x * 256 + t;
    if (t == 0) scnt = 0;
    __syncthreads();

    float v1 = -1e30f, v2 = -1e30f;
    int n1 = 0;
    for (int nn = 0; nn < 64; ++nn) {
        const float v = Sa[(size_t)nn * B_N + b];
        if (v > v1) { v2 = v1; v1 = v; n1 = nn; }
        else v2 = fmaxf(v2, v);
    }
    out[1 + b] = (float)n1;
    if (v1 - v2 < TAU) { const int idx = atomicAdd(&scnt, 1); sflags[idx] = b; }

    float err = nrm[b] - v1;
    for (int off = 32; off; off >>= 1) err += __shfl_xor(err, off, 64);
    if (lane == 0) { ssum[w] = err; scorr[w] = 0.0f; }
    __syncthreads();

    // cooperative exact rescoring of this block's flagged samples
    const int nf = scnt;
    float corr = 0.0f;
    for (int f = w; f < nf; f += 4) {
        const int b2 = sflags[f];
        const float v = Sa[(size_t)lane * B_N + b2];
        float vm = v;
        for (int off = 32; off; off >>= 1) vm = fmaxf(vm, __shfl_xor(vm, off, 64));
        unsigned long long mask = __ballot((vm - v) < TAU);
        float best = -1e30f;
        int bn = 0;
        while (mask) {
            const int nn = (int)__builtin_ctzll(mask);
            mask &= mask - 1;
            const float* Qn = Qg + (size_t)nn * 8192;
            const float* xb = x + (size_t)b2 * 128;
            float dot = 0.0f;
            #pragma unroll 8
            for (int i = 0; i < 128; ++i)
                dot = fmaf(Qn[i * 64 + lane], xb[i], dot);
            float sv = dot * dot;
            for (int off = 32; off; off >>= 1) sv += __shfl_xor(sv, off, 64);
            if (sv > best) { best = sv; bn = nn; }
        }
        if (lane == 0) {
            out[1 + b2] = (float)bn;
            corr += vm - best;   // replace approx top score with exact best
        }
    }
    if (lane == 0 && corr != 0.0f) scorr[w] += corr;
    __syncthreads();
    if (t == 0)
        atomicAdd(out, ssum[0] + ssum[1] + ssum[2] + ssum[3] +
                       scorr[0] + scorr[1] + scorr[2] + scorr[3]);
}

// ---------------------------------------------------------------------------
extern "C" void kernel_launch(void* const* d_in, const int* in_sizes, int n_in,
                              void* d_out, int out_size, void* d_ws, size_t ws_size,
                              hipStream_t stream) {
    const float* x = (const float*)d_in[0];   // [16384, 128]
    const float* D = (const float*)d_in[1];   // [64, 128, 64]
    float* out = (float*)d_out;               // [1 + 16384]

    char* ws = (char*)d_ws;
    unsigned short* xh  = (unsigned short*)(ws);                 // 4 MB
    unsigned short* Bht = (unsigned short*)(ws + (4u << 20));    // 1 MB
    float* Qg           = (float*)(ws + (5u << 20));             // 2 MB
    float* Sa           = (float*)(ws + (7u << 20));             // 4 MB
    float* nrm          = (float*)(ws + (11u << 20));            // 64 KB

    prep_convert<<<192, 256, 0, stream>>>(x, D, xh, nrm, Qg, Bht, out);
    gemm_scores<<<dim3(128, 32), 256, 0, stream>>>(xh, Bht, Sa);
    argmax_rescore<<<64, 256, 0, stream>>>(Sa, nrm, x, Qg, out);
}

// Round 6
// 175.124 us; speedup vs baseline: 2.6834x; 1.2287x over previous
//
#include <hip/hip_runtime.h>
#include <hip/hip_bf16.h>

#define B_N 16384
#define TAU 0.25f
#define GS 68     // G leading dim (floats); 16B-aligned rows
#define YS 132    // Y leading dim (floats); 16B-aligned rows

typedef float f32x4 __attribute__((ext_vector_type(4)));
typedef short s16x8 __attribute__((ext_vector_type(8)));

__device__ __forceinline__ void gl_lds16(const void* g, void* l) {
    __builtin_amdgcn_global_load_lds(
        (const __attribute__((address_space(1))) void*)g,
        (__attribute__((address_space(3))) void*)l, 16, 0, 0);
}

__device__ __forceinline__ unsigned short bf16_bits(float v) {
    __hip_bfloat16 h = __float2bfloat16(v);
    return *reinterpret_cast<unsigned short*>(&h);
}

// ---------------------------------------------------------------------------
// Kernel 1 (merged): blocks 0..63 = per-cluster prep; blocks 64..191 = convert.
// (unchanged from R5 — known-good; kept intact so rocprof isolates its cost)
// ---------------------------------------------------------------------------
__global__ __launch_bounds__(256) void prep_convert(const float* __restrict__ x,
                                                    const float* __restrict__ D,
                                                    unsigned short* __restrict__ xh,
                                                    float* __restrict__ nrm,
                                                    float* __restrict__ Qg,
                                                    unsigned short* __restrict__ Bht,
                                                    float* __restrict__ out) {
    __shared__ __align__(16) float Y[64 * YS];        // D^T -> Q^T (in place)
    __shared__ __align__(16) float G[64 * GS + 64];   // gram -> L; tail = 1/L[i][i]
    __shared__ __align__(16) float Lti[8 * 8 * 8];    // 8x8 diag-block inverses
    const int t = threadIdx.x;

    if (blockIdx.x >= 64) {
        // ---------------- convert path ----------------
        const int gid = (blockIdx.x - 64) * 256 + t;   // 0..32767 half-rows
        if (gid == 0) out[0] = 0.0f;
        const size_t base = (size_t)gid * 64;
        float s = 0.0f;
        #pragma unroll
        for (int c = 0; c < 16; ++c) {
            const f32x4 v = ((const f32x4*)(x + base))[c];
            s += v.x * v.x + v.y * v.y + v.z * v.z + v.w * v.w;
            ushort4 h;
            h.x = bf16_bits(v.x); h.y = bf16_bits(v.y);
            h.z = bf16_bits(v.z); h.w = bf16_bits(v.w);
            ((ushort4*)(xh + base))[c] = h;
        }
        s += __shfl_xor(s, 1, 64);
        if ((gid & 1) == 0) nrm[gid >> 1] = s;
        return;
    }

    // ---------------- prep path ----------------
    const int n = blockIdx.x;
    const float* Dn = D + (size_t)n * 8192;

    // Phase A: Y[j][c] = Dn[c][j]  (coalesced f32x4 global reads)
    for (int e4 = t; e4 < 2048; e4 += 256) {
        const int c = e4 >> 4, j4 = (e4 & 15) * 4;
        const f32x4 v = ((const f32x4*)Dn)[e4];
        Y[(j4 + 0) * YS + c] = v.x;
        Y[(j4 + 1) * YS + c] = v.y;
        Y[(j4 + 2) * YS + c] = v.z;
        Y[(j4 + 3) * YS + c] = v.w;
    }
    __syncthreads();

    // Phase B: gram G[a][b] = sum_c Y[a][c]*Y[b][c]
    {
        const int a0 = (t & 15) * 4, b0 = (t >> 4) * 4;
        float acc[4][4] = {};
        for (int c4 = 0; c4 < 32; ++c4) {
            f32x4 A[4], Bv[4];
            #pragma unroll
            for (int p = 0; p < 4; ++p) {
                A[p]  = *(const f32x4*)&Y[(a0 + p) * YS + c4 * 4];
                Bv[p] = *(const f32x4*)&Y[(b0 + p) * YS + c4 * 4];
            }
            #pragma unroll
            for (int p = 0; p < 4; ++p)
                #pragma unroll
                for (int q = 0; q < 4; ++q)
                    acc[p][q] += A[p].x * Bv[q].x + A[p].y * Bv[q].y +
                                 A[p].z * Bv[q].z + A[p].w * Bv[q].w;
        }
        #pragma unroll
        for (int p = 0; p < 4; ++p)
            #pragma unroll
            for (int q = 0; q < 4; ++q) G[(a0 + p) * GS + b0 + q] = acc[p][q];
    }
    __syncthreads();

    // Phase C: blocked Cholesky, register-resident 8x8 panel factors
    for (int p8 = 0; p8 < 8; ++p8) {
        const int pb = p8 * 8;
        if (t < 64) {   // wave 0
            const int lane = t;
            const f32x4 v0 = *(const f32x4*)&G[lane * GS + pb];
            const f32x4 v1 = *(const f32x4*)&G[lane * GS + pb + 4];
            float g[8] = {v0.x, v0.y, v0.z, v0.w, v1.x, v1.y, v1.z, v1.w};
            #pragma unroll
            for (int kk = 0; kk < 8; ++kk) {
                const int k = pb + kk;
                const float dk = __shfl(g[kk], k, 64);
                const float rinv = 1.0f / sqrtf(dk);
                const float lik = g[kk] * rinv;
                g[kk] = lik;
                if (lane == 0) G[64 * GS + k] = rinv;
                #pragma unroll
                for (int jj = kk + 1; jj < 8; ++jj) {
                    const float ljk = __shfl(lik, pb + jj, 64);
                    g[jj] -= lik * ljk;
                }
            }
            *(f32x4*)&G[lane * GS + pb]     = (f32x4){g[0], g[1], g[2], g[3]};
            *(f32x4*)&G[lane * GS + pb + 4] = (f32x4){g[4], g[5], g[6], g[7]};
        }
        __syncthreads();
        const int base = pb + 8;
        if (base < 64) {   // rank-8 trailing update, all 256 threads
            for (int i = base + (t >> 5); i < 64; i += 8) {
                const f32x4 Li0 = *(const f32x4*)&G[i * GS + pb];
                const f32x4 Li1 = *(const f32x4*)&G[i * GS + pb + 4];
                for (int j = base + (t & 31); j < 64; j += 32) {
                    const f32x4 Lj0 = *(const f32x4*)&G[j * GS + pb];
                    const f32x4 Lj1 = *(const f32x4*)&G[j * GS + pb + 4];
                    float s = G[i * GS + j];
                    s -= Li0.x * Lj0.x + Li0.y * Lj0.y + Li0.z * Lj0.z + Li0.w * Lj0.w;
                    s -= Li1.x * Lj1.x + Li1.y * Lj1.y + Li1.z * Lj1.z + Li1.w * Lj1.w;
                    G[i * GS + j] = s;
                }
            }
        }
        __syncthreads();
    }

    // Phase D: invert 8x8 diagonal blocks independently. t<64: block bi, col c.
    if (t < 64) {
        const int bi = t >> 3, c = t & 7;
        const int base = bi * 8;
        float m[8];
        #pragma unroll
        for (int r = 0; r < 8; ++r) {
            float s = (r == c) ? 1.0f : 0.0f;
            #pragma unroll
            for (int k = 0; k < r; ++k)
                s -= G[(base + r) * GS + base + k] * m[k];
            m[r] = s * G[64 * GS + base + r];
        }
        #pragma unroll
        for (int r = 0; r < 8; ++r) Lti[(base + r) * 8 + c] = m[r];
    }
    __syncthreads();

    // Phase E: Q^T = L^{-1} D^T, block forward substitution; thread = column c.
    if (t < 128) {
        const int c = t;
        for (int i = 0; i < 8; ++i) {
            float Tv[8];
            #pragma unroll
            for (int r = 0; r < 8; ++r) Tv[r] = Y[(i * 8 + r) * YS + c];
            for (int k = 0; k < i; ++k) {
                #pragma unroll
                for (int kk = 0; kk < 8; ++kk) {
                    const float z = Y[(k * 8 + kk) * YS + c];
                    #pragma unroll
                    for (int r = 0; r < 8; ++r)
                        Tv[r] -= G[(i * 8 + r) * GS + k * 8 + kk] * z;
                }
            }
            #pragma unroll
            for (int r = 0; r < 8; ++r) {
                float z = 0.0f;
                #pragma unroll
                for (int rp = 0; rp <= r; ++rp)
                    z += Lti[(i * 8 + r) * 8 + rp] * Tv[rp];
                Y[(i * 8 + r) * YS + c] = z;
            }
        }
    }
    __syncthreads();

    // Phase F: outputs. Y[j][i] = Q^T.
    for (int e = t; e < 8192; e += 256) {
        const int j = e >> 7, i = e & 127;
        Bht[((size_t)n * 64 + j) * 128 + i] = bf16_bits(Y[j * YS + i]);
    }
    for (int e = t; e < 8192; e += 256) {
        const int i = e >> 6, j = e & 63;
        Qg[(size_t)n * 8192 + e] = Y[j * YS + i];
    }
}

// ---------------------------------------------------------------------------
// Kernel 2: MFMA scores. (unchanged, known-good)
// ---------------------------------------------------------------------------
__global__ __launch_bounds__(256) void gemm_scores(const unsigned short* __restrict__ xh,
                                                   const unsigned short* __restrict__ Bht,
                                                   float* __restrict__ S) {
    __shared__ unsigned short ldsA[128 * 64];   // 16 KB
    __shared__ unsigned short ldsB[128 * 64];   // 16 KB
    const int t = threadIdx.x, w = t >> 6, lane = t & 63;
    const int m0 = blockIdx.x * 128;
    const int n0 = blockIdx.y * 128;
    const int wm = w & 1, wn = w >> 1;

    f32x4 acc[4][4];
    #pragma unroll
    for (int mt = 0; mt < 4; ++mt)
        #pragma unroll
        for (int nt = 0; nt < 4; ++nt) acc[mt][nt] = (f32x4){0.f, 0.f, 0.f, 0.f};

    #pragma unroll 1
    for (int it = 0; it < 2; ++it) {
        const int ko = it * 64;
        __syncthreads();
        #pragma unroll
        for (int q = 0; q < 4; ++q) {
            const int r = w * 32 + q * 8 + (lane >> 3);
            const int cb = (lane & 7) ^ (r & 7);
            gl_lds16(xh + (size_t)(m0 + r) * 128 + ko + cb * 8,
                     &ldsA[(w * 32 + q * 8) * 64]);
            gl_lds16(Bht + (size_t)(n0 + r) * 128 + ko + cb * 8,
                     &ldsB[(w * 32 + q * 8) * 64]);
        }
        __syncthreads();
        #pragma unroll
        for (int ks = 0; ks < 2; ++ks) {
            s16x8 af[4], bf[4];
            #pragma unroll
            for (int mt = 0; mt < 4; ++mt) {
                const int r = wm * 64 + mt * 16 + (lane & 15);
                const int s = (ks * 4 + (lane >> 4)) ^ (r & 7);
                af[mt] = *(const s16x8*)&ldsA[r * 64 + s * 8];
            }
            #pragma unroll
            for (int nt = 0; nt < 4; ++nt) {
                const int r = wn * 64 + nt * 16 + (lane & 15);
                const int s = (ks * 4 + (lane >> 4)) ^ (r & 7);
                bf[nt] = *(const s16x8*)&ldsB[r * 64 + s * 8];
            }
            #pragma unroll
            for (int mt = 0; mt < 4; ++mt)
                #pragma unroll
                for (int nt = 0; nt < 4; ++nt)
                    acc[mt][nt] = __builtin_amdgcn_mfma_f32_16x16x32_bf16(
                        af[mt], bf[nt], acc[mt][nt], 0, 0, 0);
        }
    }

    const int nc = blockIdx.y * 2 + wn;
    #pragma unroll
    for (int mt = 0; mt < 4; ++mt) {
        #pragma unroll
        for (int rg = 0; rg < 4; ++rg) {
            float p = 0.0f;
            #pragma unroll
            for (int nt = 0; nt < 4; ++nt) {
                const float v = acc[mt][nt][rg];
                p += v * v;
            }
            p += __shfl_xor(p, 1, 64);
            p += __shfl_xor(p, 2, 64);
            p += __shfl_xor(p, 4, 64);
            p += __shfl_xor(p, 8, 64);
            if ((lane & 15) == 0) {
                const int m = wm * 64 + mt * 16 + (lane >> 4) * 4 + rg;
                S[(size_t)nc * B_N + m0 + m] = p;
            }
        }
    }
}

// ---------------------------------------------------------------------------
// Kernel 3: argmax + loss + exact rescore, LDS-transposed S tile.
// 256 blocks x 64 samples. R5's 76 us was the Sa column gather (64 KB stride,
// 4 KB HBM per flagged sample) + 1-wave/CU latency; now every S access after
// the coalesced tile load is LDS (pad 65 -> all phases <=2-way on banks).
// ---------------------------------------------------------------------------
__global__ __launch_bounds__(256) void argmax_rescore(const float* __restrict__ Sa,
                                                      const float* __restrict__ nrm,
                                                      const float* __restrict__ x,
                                                      const float* __restrict__ Qg,
                                                      float* __restrict__ out) {
    __shared__ float tile[64 * 65];   // [sample][n], 16640 B
    __shared__ int sflags[64];
    __shared__ int scnt;
    __shared__ float ssum;
    __shared__ float scorr[4];
    const int t = threadIdx.x, w = t >> 6, lane = t & 63;
    const int b0 = blockIdx.x * 64;
    if (t == 0) scnt = 0;

    // coalesced load + transpose: Sa[n][b0 + c] -> tile[c][n]
    for (int idx = t; idx < 1024; idx += 256) {
        const int n = idx >> 4, c4 = idx & 15;
        const f32x4 v = *(const f32x4*)&Sa[(size_t)n * B_N + b0 + c4 * 4];
        tile[(c4 * 4 + 0) * 65 + n] = v.x;
        tile[(c4 * 4 + 1) * 65 + n] = v.y;
        tile[(c4 * 4 + 2) * 65 + n] = v.z;
        tile[(c4 * 4 + 3) * 65 + n] = v.w;
    }
    __syncthreads();

    // per-thread argmax (wave 0), flag near-ties, wave-reduced loss
    if (t < 64) {
        float v1 = -1e30f, v2 = -1e30f;
        int n1 = 0;
        for (int n = 0; n < 64; ++n) {
            const float v = tile[t * 65 + n];
            if (v > v1) { v2 = v1; v1 = v; n1 = n; }
            else v2 = fmaxf(v2, v);
        }
        out[1 + b0 + t] = (float)n1;
        if (v1 - v2 < TAU) { const int i = atomicAdd(&scnt, 1); sflags[i] = t; }
        float err = nrm[b0 + t] - v1;
        for (int off = 32; off; off >>= 1) err += __shfl_xor(err, off, 64);
        if (t == 0) ssum = err;
    }
    if (lane == 0) scorr[w] = 0.0f;
    __syncthreads();

    // cooperative exact rescore of flagged samples (S column from LDS)
    const int nf = scnt;
    float corr = 0.0f;
    for (int f = w; f < nf; f += 4) {
        const int s = sflags[f];
        const int b2 = b0 + s;
        const float v = tile[s * 65 + lane];
        float vm = v;
        for (int off = 32; off; off >>= 1) vm = fmaxf(vm, __shfl_xor(vm, off, 64));
        unsigned long long mask = __ballot((vm - v) < TAU);
        float best = -1e30f;
        int bn = 0;
        while (mask) {
            const int nn = (int)__builtin_ctzll(mask);
            mask &= mask - 1;
            const float* Qn = Qg + (size_t)nn * 8192;
            const float* xb = x + (size_t)b2 * 128;
            float dot = 0.0f;
            #pragma unroll 8
            for (int i = 0; i < 128; ++i)
                dot = fmaf(Qn[i * 64 + lane], xb[i], dot);
            float sv = dot * dot;
            for (int off = 32; off; off >>= 1) sv += __shfl_xor(sv, off, 64);
            if (sv > best) { best = sv; bn = nn; }
        }
        if (lane == 0) {
            out[1 + b2] = (float)bn;
            corr += vm - best;   // replace approx top score with exact best
        }
    }
    if (lane == 0 && corr != 0.0f) scorr[w] += corr;
    __syncthreads();
    if (t == 0)
        atomicAdd(out, ssum + scorr[0] + scorr[1] + scorr[2] + scorr[3]);
}

// ---------------------------------------------------------------------------
extern "C" void kernel_launch(void* const* d_in, const int* in_sizes, int n_in,
                              void* d_out, int out_size, void* d_ws, size_t ws_size,
                              hipStream_t stream) {
    const float* x = (const float*)d_in[0];   // [16384, 128]
    const float* D = (const float*)d_in[1];   // [64, 128, 64]
    float* out = (float*)d_out;               // [1 + 16384]

    char* ws = (char*)d_ws;
    unsigned short* xh  = (unsigned short*)(ws);                 // 4 MB
    unsigned short* Bht = (unsigned short*)(ws + (4u << 20));    // 1 MB
    float* Qg           = (float*)(ws + (5u << 20));             // 2 MB
    float* Sa           = (float*)(ws + (7u << 20));             // 4 MB
    float* nrm          = (float*)(ws + (11u << 20));            // 64 KB

    prep_convert<<<192, 256, 0, stream>>>(x, D, xh, nrm, Qg, Bht, out);
    gemm_scores<<<dim3(128, 32), 256, 0, stream>>>(xh, Bht, Sa);
    argmax_rescore<<<256, 256, 0, stream>>>(Sa, nrm, x, Qg, out);
}

// Round 7
// 164.081 us; speedup vs baseline: 2.8640x; 1.0673x over previous
//
#include <hip/hip_runtime.h>
#include <hip/hip_bf16.h>

#define B_N 16384
#define TAU 0.25f
#define GS 68     // G leading dim (floats); 16B-aligned rows
#define YS 132    // Y leading dim (floats); 16B-aligned rows

typedef float f32x4 __attribute__((ext_vector_type(4)));
typedef short s16x8 __attribute__((ext_vector_type(8)));

__device__ __forceinline__ void gl_lds16(const void* g, void* l) {
    __builtin_amdgcn_global_load_lds(
        (const __attribute__((address_space(1))) void*)g,
        (__attribute__((address_space(3))) void*)l, 16, 0, 0);
}

__device__ __forceinline__ unsigned short bf16_bits(float v) {
    __hip_bfloat16 h = __float2bfloat16(v);
    return *reinterpret_cast<unsigned short*>(&h);
}

// ---------------------------------------------------------------------------
// Kernel 1 (merged): blocks 0..63 = per-cluster prep; blocks 64..191 = convert.
// (byte-identical to R5/R6 — kept for clean attribution)
// ---------------------------------------------------------------------------
__global__ __launch_bounds__(256) void prep_convert(const float* __restrict__ x,
                                                    const float* __restrict__ D,
                                                    unsigned short* __restrict__ xh,
                                                    float* __restrict__ nrm,
                                                    float* __restrict__ Qg,
                                                    unsigned short* __restrict__ Bht,
                                                    float* __restrict__ out) {
    __shared__ __align__(16) float Y[64 * YS];        // D^T -> Q^T (in place)
    __shared__ __align__(16) float G[64 * GS + 64];   // gram -> L; tail = 1/L[i][i]
    __shared__ __align__(16) float Lti[8 * 8 * 8];    // 8x8 diag-block inverses
    const int t = threadIdx.x;

    if (blockIdx.x >= 64) {
        // ---------------- convert path ----------------
        const int gid = (blockIdx.x - 64) * 256 + t;   // 0..32767 half-rows
        if (gid == 0) out[0] = 0.0f;
        const size_t base = (size_t)gid * 64;
        float s = 0.0f;
        #pragma unroll
        for (int c = 0; c < 16; ++c) {
            const f32x4 v = ((const f32x4*)(x + base))[c];
            s += v.x * v.x + v.y * v.y + v.z * v.z + v.w * v.w;
            ushort4 h;
            h.x = bf16_bits(v.x); h.y = bf16_bits(v.y);
            h.z = bf16_bits(v.z); h.w = bf16_bits(v.w);
            ((ushort4*)(xh + base))[c] = h;
        }
        s += __shfl_xor(s, 1, 64);
        if ((gid & 1) == 0) nrm[gid >> 1] = s;
        return;
    }

    // ---------------- prep path ----------------
    const int n = blockIdx.x;
    const float* Dn = D + (size_t)n * 8192;

    // Phase A: Y[j][c] = Dn[c][j]  (coalesced f32x4 global reads)
    for (int e4 = t; e4 < 2048; e4 += 256) {
        const int c = e4 >> 4, j4 = (e4 & 15) * 4;
        const f32x4 v = ((const f32x4*)Dn)[e4];
        Y[(j4 + 0) * YS + c] = v.x;
        Y[(j4 + 1) * YS + c] = v.y;
        Y[(j4 + 2) * YS + c] = v.z;
        Y[(j4 + 3) * YS + c] = v.w;
    }
    __syncthreads();

    // Phase B: gram G[a][b] = sum_c Y[a][c]*Y[b][c]
    {
        const int a0 = (t & 15) * 4, b0 = (t >> 4) * 4;
        float acc[4][4] = {};
        for (int c4 = 0; c4 < 32; ++c4) {
            f32x4 A[4], Bv[4];
            #pragma unroll
            for (int p = 0; p < 4; ++p) {
                A[p]  = *(const f32x4*)&Y[(a0 + p) * YS + c4 * 4];
                Bv[p] = *(const f32x4*)&Y[(b0 + p) * YS + c4 * 4];
            }
            #pragma unroll
            for (int p = 0; p < 4; ++p)
                #pragma unroll
                for (int q = 0; q < 4; ++q)
                    acc[p][q] += A[p].x * Bv[q].x + A[p].y * Bv[q].y +
                                 A[p].z * Bv[q].z + A[p].w * Bv[q].w;
        }
        #pragma unroll
        for (int p = 0; p < 4; ++p)
            #pragma unroll
            for (int q = 0; q < 4; ++q) G[(a0 + p) * GS + b0 + q] = acc[p][q];
    }
    __syncthreads();

    // Phase C: blocked Cholesky, register-resident 8x8 panel factors
    for (int p8 = 0; p8 < 8; ++p8) {
        const int pb = p8 * 8;
        if (t < 64) {   // wave 0
            const int lane = t;
            const f32x4 v0 = *(const f32x4*)&G[lane * GS + pb];
            const f32x4 v1 = *(const f32x4*)&G[lane * GS + pb + 4];
            float g[8] = {v0.x, v0.y, v0.z, v0.w, v1.x, v1.y, v1.z, v1.w};
            #pragma unroll
            for (int kk = 0; kk < 8; ++kk) {
                const int k = pb + kk;
                const float dk = __shfl(g[kk], k, 64);
                const float rinv = 1.0f / sqrtf(dk);
                const float lik = g[kk] * rinv;
                g[kk] = lik;
                if (lane == 0) G[64 * GS + k] = rinv;
                #pragma unroll
                for (int jj = kk + 1; jj < 8; ++jj) {
                    const float ljk = __shfl(lik, pb + jj, 64);
                    g[jj] -= lik * ljk;
                }
            }
            *(f32x4*)&G[lane * GS + pb]     = (f32x4){g[0], g[1], g[2], g[3]};
            *(f32x4*)&G[lane * GS + pb + 4] = (f32x4){g[4], g[5], g[6], g[7]};
        }
        __syncthreads();
        const int base = pb + 8;
        if (base < 64) {   // rank-8 trailing update, all 256 threads
            for (int i = base + (t >> 5); i < 64; i += 8) {
                const f32x4 Li0 = *(const f32x4*)&G[i * GS + pb];
                const f32x4 Li1 = *(const f32x4*)&G[i * GS + pb + 4];
                for (int j = base + (t & 31); j < 64; j += 32) {
                    const f32x4 Lj0 = *(const f32x4*)&G[j * GS + pb];
                    const f32x4 Lj1 = *(const f32x4*)&G[j * GS + pb + 4];
                    float s = G[i * GS + j];
                    s -= Li0.x * Lj0.x + Li0.y * Lj0.y + Li0.z * Lj0.z + Li0.w * Lj0.w;
                    s -= Li1.x * Lj1.x + Li1.y * Lj1.y + Li1.z * Lj1.z + Li1.w * Lj1.w;
                    G[i * GS + j] = s;
                }
            }
        }
        __syncthreads();
    }

    // Phase D: invert 8x8 diagonal blocks independently. t<64: block bi, col c.
    if (t < 64) {
        const int bi = t >> 3, c = t & 7;
        const int base = bi * 8;
        float m[8];
        #pragma unroll
        for (int r = 0; r < 8; ++r) {
            float s = (r == c) ? 1.0f : 0.0f;
            #pragma unroll
            for (int k = 0; k < r; ++k)
                s -= G[(base + r) * GS + base + k] * m[k];
            m[r] = s * G[64 * GS + base + r];
        }
        #pragma unroll
        for (int r = 0; r < 8; ++r) Lti[(base + r) * 8 + c] = m[r];
    }
    __syncthreads();

    // Phase E: Q^T = L^{-1} D^T, block forward substitution; thread = column c.
    if (t < 128) {
        const int c = t;
        for (int i = 0; i < 8; ++i) {
            float Tv[8];
            #pragma unroll
            for (int r = 0; r < 8; ++r) Tv[r] = Y[(i * 8 + r) * YS + c];
            for (int k = 0; k < i; ++k) {
                #pragma unroll
                for (int kk = 0; kk < 8; ++kk) {
                    const float z = Y[(k * 8 + kk) * YS + c];
                    #pragma unroll
                    for (int r = 0; r < 8; ++r)
                        Tv[r] -= G[(i * 8 + r) * GS + k * 8 + kk] * z;
                }
            }
            #pragma unroll
            for (int r = 0; r < 8; ++r) {
                float z = 0.0f;
                #pragma unroll
                for (int rp = 0; rp <= r; ++rp)
                    z += Lti[(i * 8 + r) * 8 + rp] * Tv[rp];
                Y[(i * 8 + r) * YS + c] = z;
            }
        }
    }
    __syncthreads();

    // Phase F: outputs. Y[j][i] = Q^T.
    for (int e = t; e < 8192; e += 256) {
        const int j = e >> 7, i = e & 127;
        Bht[((size_t)n * 64 + j) * 128 + i] = bf16_bits(Y[j * YS + i]);
    }
    for (int e = t; e < 8192; e += 256) {
        const int i = e >> 6, j = e & 63;
        Qg[(size_t)n * 8192 + e] = Y[j * YS + i];
    }
}

// ---------------------------------------------------------------------------
// Kernel 2: MFMA scores, A-register-resident. Grid (128 m-tiles, 4 n-splits).
// Block stages its A tile (128x128 bf16, full K) ONCE, holds all A-frags in
// 64 VGPRs, then loops 8 B-tiles: frag-read -> barrier -> kick next DMA ->
// 64 MFMAs (DMA overlapped) -> barrier. XOR-swizzle (colblock ^ (row&15))
// keeps DMA staging contiguous per wave and frag ds_read_b128 <=2-way.
// ---------------------------------------------------------------------------
__global__ __launch_bounds__(256) void gemm_scores(const unsigned short* __restrict__ xh,
                                                   const unsigned short* __restrict__ Bht,
                                                   float* __restrict__ S) {
    __shared__ unsigned short ldsA[128 * 128];   // 32 KB
    __shared__ unsigned short ldsB[128 * 128];   // 32 KB
    const int t = threadIdx.x, w = t >> 6, lane = t & 63;
    const int m0 = blockIdx.x * 128;
    const int nsplit = blockIdx.y;               // 16 clusters per split
    const int wm = w & 1, wn = w >> 1;

    // ---- stage A (once) and B tile 0 ----
    {
        const int rl = lane >> 4;                 // row within 4-row group
        const int p  = lane & 15;                 // physical colblock
        #pragma unroll
        for (int q = 0; q < 8; ++q) {
            const int row = w * 32 + q * 4 + rl;
            const int c = p ^ (row & 15);         // source colblock
            gl_lds16(xh + (size_t)(m0 + row) * 128 + c * 8,
                     &ldsA[(w * 32 + q * 4) * 128]);
            gl_lds16(Bht + (size_t)(nsplit * 1024 + row) * 128 + c * 8,
                     &ldsB[(w * 32 + q * 4) * 128]);
        }
    }
    __syncthreads();

    // ---- load all A-fragments into registers (64 VGPRs), resident ----
    s16x8 af[4][4];   // [mt][ks]
    #pragma unroll
    for (int mt = 0; mt < 4; ++mt) {
        const int r = wm * 64 + mt * 16 + (lane & 15);
        #pragma unroll
        for (int ks = 0; ks < 4; ++ks) {
            const int p = (ks * 4 + (lane >> 4)) ^ (lane & 15);
            af[mt][ks] = *(const s16x8*)&ldsA[r * 128 + p * 8];
        }
    }

    #pragma unroll 1
    for (int it = 0; it < 8; ++it) {
        // ---- read this tile's B-fragments ----
        s16x8 bf[4][4];   // [nt][ks]
        #pragma unroll
        for (int nt = 0; nt < 4; ++nt) {
            const int r = wn * 64 + nt * 16 + (lane & 15);
            #pragma unroll
            for (int ks = 0; ks < 4; ++ks) {
                const int p = (ks * 4 + (lane >> 4)) ^ (lane & 15);
                bf[nt][ks] = *(const s16x8*)&ldsB[r * 128 + p * 8];
            }
        }
        __syncthreads();   // all waves done reading ldsB (and ldsA on it=0)

        // ---- kick DMA for next B tile (overlaps the MFMAs below) ----
        if (it < 7) {
            const int rl = lane >> 4, p = lane & 15;
            #pragma unroll
            for (int q = 0; q < 8; ++q) {
                const int row = w * 32 + q * 4 + rl;
                const int c = p ^ (row & 15);
                gl_lds16(Bht + (size_t)(nsplit * 1024 + (it + 1) * 128 + row) * 128 + c * 8,
                         &ldsB[(w * 32 + q * 4) * 128]);
            }
        }

        // ---- 64 MFMAs ----
        f32x4 acc[4][4];
        #pragma unroll
        for (int mt = 0; mt < 4; ++mt)
            #pragma unroll
            for (int nt = 0; nt < 4; ++nt) acc[mt][nt] = (f32x4){0.f, 0.f, 0.f, 0.f};
        #pragma unroll
        for (int ks = 0; ks < 4; ++ks)
            #pragma unroll
            for (int mt = 0; mt < 4; ++mt)
                #pragma unroll
                for (int nt = 0; nt < 4; ++nt)
                    acc[mt][nt] = __builtin_amdgcn_mfma_f32_16x16x32_bf16(
                        af[mt][ks], bf[nt][ks], acc[mt][nt], 0, 0, 0);

        // ---- epilogue: wave's 64 cols = one cluster; squared-sum over cols ----
        const int nc = nsplit * 16 + it * 2 + wn;
        #pragma unroll
        for (int mt = 0; mt < 4; ++mt) {
            #pragma unroll
            for (int rg = 0; rg < 4; ++rg) {
                float p = 0.0f;
                #pragma unroll
                for (int nt = 0; nt < 4; ++nt) {
                    const float v = acc[mt][nt][rg];
                    p += v * v;
                }
                p += __shfl_xor(p, 1, 64);
                p += __shfl_xor(p, 2, 64);
                p += __shfl_xor(p, 4, 64);
                p += __shfl_xor(p, 8, 64);
                if ((lane & 15) == 0) {
                    const int m = wm * 64 + mt * 16 + (lane >> 4) * 4 + rg;
                    S[(size_t)nc * B_N + m0 + m] = p;
                }
            }
        }
        __syncthreads();   // drains this wave's DMA -> ldsB holds tile it+1
    }
}

// ---------------------------------------------------------------------------
// Kernel 3: argmax + loss + exact rescore, LDS-transposed S tile.
// (byte-identical to R6 — known-good)
// ---------------------------------------------------------------------------
__global__ __launch_bounds__(256) void argmax_rescore(const float* __restrict__ Sa,
                                                      const float* __restrict__ nrm,
                                                      const float* __restrict__ x,
                                                      const float* __restrict__ Qg,
                                                      float* __restrict__ out) {
    __shared__ float tile[64 * 65];   // [sample][n], 16640 B
    __shared__ int sflags[64];
    __shared__ int scnt;
    __shared__ float ssum;
    __shared__ float scorr[4];
    const int t = threadIdx.x, w = t >> 6, lane = t & 63;
    const int b0 = blockIdx.x * 64;
    if (t == 0) scnt = 0;

    // coalesced load + transpose: Sa[n][b0 + c] -> tile[c][n]
    for (int idx = t; idx < 1024; idx += 256) {
        const int n = idx >> 4, c4 = idx & 15;
        const f32x4 v = *(const f32x4*)&Sa[(size_t)n * B_N + b0 + c4 * 4];
        tile[(c4 * 4 + 0) * 65 + n] = v.x;
        tile[(c4 * 4 + 1) * 65 + n] = v.y;
        tile[(c4 * 4 + 2) * 65 + n] = v.z;
        tile[(c4 * 4 + 3) * 65 + n] = v.w;
    }
    __syncthreads();

    // per-thread argmax (wave 0), flag near-ties, wave-reduced loss
    if (t < 64) {
        float v1 = -1e30f, v2 = -1e30f;
        int n1 = 0;
        for (int n = 0; n < 64; ++n) {
            const float v = tile[t * 65 + n];
            if (v > v1) { v2 = v1; v1 = v; n1 = n; }
            else v2 = fmaxf(v2, v);
        }
        out[1 + b0 + t] = (float)n1;
        if (v1 - v2 < TAU) { const int i = atomicAdd(&scnt, 1); sflags[i] = t; }
        float err = nrm[b0 + t] - v1;
        for (int off = 32; off; off >>= 1) err += __shfl_xor(err, off, 64);
        if (t == 0) ssum = err;
    }
    if (lane == 0) scorr[w] = 0.0f;
    __syncthreads();

    // cooperative exact rescore of flagged samples (S column from LDS)
    const int nf = scnt;
    float corr = 0.0f;
    for (int f = w; f < nf; f += 4) {
        const int s = sflags[f];
        const int b2 = b0 + s;
        const float v = tile[s * 65 + lane];
        float vm = v;
        for (int off = 32; off; off >>= 1) vm = fmaxf(vm, __shfl_xor(vm, off, 64));
        unsigned long long mask = __ballot((vm - v) < TAU);
        float best = -1e30f;
        int bn = 0;
        while (mask) {
            const int nn = (int)__builtin_ctzll(mask);
            mask &= mask - 1;
            const float* Qn = Qg + (size_t)nn * 8192;
            const float* xb = x + (size_t)b2 * 128;
            float dot = 0.0f;
            #pragma unroll 8
            for (int i = 0; i < 128; ++i)
                dot = fmaf(Qn[i * 64 + lane], xb[i], dot);
            float sv = dot * dot;
            for (int off = 32; off; off >>= 1) sv += __shfl_xor(sv, off, 64);
            if (sv > best) { best = sv; bn = nn; }
        }
        if (lane == 0) {
            out[1 + b2] = (float)bn;
            corr += vm - best;   // replace approx top score with exact best
        }
    }
    if (lane == 0 && corr != 0.0f) scorr[w] += corr;
    __syncthreads();
    if (t == 0)
        atomicAdd(out, ssum + scorr[0] + scorr[1] + scorr[2] + scorr[3]);
}

// ---------------------------------------------------------------------------
extern "C" void kernel_launch(void* const* d_in, const int* in_sizes, int n_in,
                              void* d_out, int out_size, void* d_ws, size_t ws_size,
                              hipStream_t stream) {
    const float* x = (const float*)d_in[0];   // [16384, 128]
    const float* D = (const float*)d_in[1];   // [64, 128, 64]
    float* out = (float*)d_out;               // [1 + 16384]

    char* ws = (char*)d_ws;
    unsigned short* xh  = (unsigned short*)(ws);                 // 4 MB
    unsigned short* Bht = (unsigned short*)(ws + (4u << 20));    // 1 MB
    float* Qg           = (float*)(ws + (5u << 20));             // 2 MB
    float* Sa           = (float*)(ws + (7u << 20));             // 4 MB
    float* nrm          = (float*)(ws + (11u << 20));            // 64 KB

    prep_convert<<<192, 256, 0, stream>>>(x, D, xh, nrm, Qg, Bht, out);
    gemm_scores<<<dim3(128, 4), 256, 0, stream>>>(xh, Bht, Sa);
    argmax_rescore<<<256, 256, 0, stream>>>(Sa, nrm, x, Qg, out);
}